// Round 3
// baseline (1794.351 us; speedup 1.0000x reference)
//
#include <hip/hip_runtime.h>
#include <hip/hip_bf16.h>

// ---------------------------------------------------------------------------
// TransformerDecoderLayer on MI355X (gfx950). fp32 I/O, bf16 MFMA GEMMs with
// fp32 accumulation, fp32 VALU flash attention, fp32 LayerNorm.
// T=S=1024, B=4, D=1024, H=16, HD=64, FFN=4096.
// ---------------------------------------------------------------------------

typedef __attribute__((ext_vector_type(8))) short bf16x8;
typedef __attribute__((ext_vector_type(4))) float f32x4;
typedef __attribute__((ext_vector_type(8))) unsigned short us8;
typedef __attribute__((ext_vector_type(4))) unsigned short us4;

#define AS1 __attribute__((address_space(1)))
#define AS3 __attribute__((address_space(3)))

#define T_LEN 1024
#define S_LEN 1024
#define B_DIM 4
#define D_MOD 1024
#define H_NUM 16
#define FFN_D 4096
#define NTOK  4096   /* T*B rows of the token matrix */

__device__ __forceinline__ float b2f(unsigned short u) {
    return __uint_as_float(((unsigned int)u) << 16);
}
__device__ __forceinline__ unsigned short f2b(float f) {
    unsigned int x = __float_as_uint(f);
    x += 0x7fffu + ((x >> 16) & 1u);   // RNE
    return (unsigned short)(x >> 16);
}

// ---------------------------------------------------------------------------
// fp32 -> bf16 conversion, 8 elems/thread, grid-stride.
// ---------------------------------------------------------------------------
__global__ __launch_bounds__(256) void cvt_kernel(
    const float* __restrict__ in, unsigned short* __restrict__ out, int n8)
{
    int i = blockIdx.x * 256 + threadIdx.x;
    const int stride = gridDim.x * 256;
    for (; i < n8; i += stride) {
        const f32x4 a = *(const f32x4*)&in[(size_t)i * 8];
        const f32x4 b = *(const f32x4*)&in[(size_t)i * 8 + 4];
        us8 o;
#pragma unroll
        for (int j = 0; j < 4; ++j) { o[j] = f2b(a[j]); o[4 + j] = f2b(b[j]); }
        *(us8*)&out[(size_t)i * 8] = o;
    }
}

// ---------------------------------------------------------------------------
// GEMM: out[M,N] = A[M,K](bf16) @ W[N,K]^T(bf16)  + bias(f32)
//       [rowmask-zero of matmul term] [relu] [+residual(f32)]
// Writes out_f (f32) and/or out_bf (bf16), either may be null.
// 128x128 tile, BK=32, 4 waves (2x2), mfma_f32_16x16x32_bf16, fp32 accum.
// Token rows are r = s*B_DIM + b; rowmask is [B_DIM, M/B_DIM] ints (!=0 = pad).
// ---------------------------------------------------------------------------
__global__ __launch_bounds__(256, 2) void gemm_bt_kernel(
    const unsigned short* __restrict__ A,
    const unsigned short* __restrict__ W,
    const float* __restrict__ bias,
    const float* __restrict__ residual,
    const int* __restrict__ rowmask,
    unsigned short* __restrict__ out_bf,
    float* __restrict__ out_f,
    int M, int N, int K, int relu)
{
    __shared__ __align__(16) unsigned short As[128 * 32];
    __shared__ __align__(16) unsigned short Bs[128 * 32];

    const int tid  = threadIdx.x;
    const int lane = tid & 63;
    const int wid  = tid >> 6;
    const int wr   = wid >> 1, wc = wid & 1;
    const int row0 = blockIdx.x * 128;
    const int col0 = blockIdx.y * 128;

    f32x4 acc[4][4];
#pragma unroll
    for (int m = 0; m < 4; ++m)
#pragma unroll
        for (int n = 0; n < 4; ++n)
            acc[m][n] = (f32x4){0.f, 0.f, 0.f, 0.f};

    const int arow = tid >> 2;          // 0..63
    const int acol = (tid & 3) * 8;     // element col within BK

    for (int k0 = 0; k0 < K; k0 += 32) {
#pragma unroll
        for (int j = 0; j < 2; ++j) {
            const unsigned short* srcA = A + (size_t)(row0 + j * 64 + arow) * K + k0 + acol;
            __builtin_amdgcn_global_load_lds((const AS1 void*)srcA,
                (AS3 void*)(&As[(j * 64 + arow) * 32 + acol]), 16, 0, 0);
            const unsigned short* srcB = W + (size_t)(col0 + j * 64 + arow) * K + k0 + acol;
            __builtin_amdgcn_global_load_lds((const AS1 void*)srcB,
                (AS3 void*)(&Bs[(j * 64 + arow) * 32 + acol]), 16, 0, 0);
        }
        __syncthreads();

        const int kg   = (lane >> 4) * 8;
        const int rsel = lane & 15;
        bf16x8 a[4], b[4];
#pragma unroll
        for (int m = 0; m < 4; ++m)
            a[m] = *(const bf16x8*)&As[(wr * 64 + m * 16 + rsel) * 32 + kg];
#pragma unroll
        for (int n = 0; n < 4; ++n)
            b[n] = *(const bf16x8*)&Bs[(wc * 64 + n * 16 + rsel) * 32 + kg];
#pragma unroll
        for (int m = 0; m < 4; ++m)
#pragma unroll
            for (int n = 0; n < 4; ++n)
                acc[m][n] = __builtin_amdgcn_mfma_f32_16x16x32_bf16(a[m], b[n], acc[m][n], 0, 0, 0);
        __syncthreads();
    }

    // epilogue: C/D layout col=lane&15, row=(lane>>4)*4+j  [measured m89/m91]
    const int csel = lane & 15;
    const int rbas = (lane >> 4) * 4;
    const int seq  = M >> 2;            // M / B_DIM
#pragma unroll
    for (int m = 0; m < 4; ++m) {
#pragma unroll
        for (int n = 0; n < 4; ++n) {
#pragma unroll
            for (int j = 0; j < 4; ++j) {
                const int gr = row0 + wr * 64 + m * 16 + rbas + j;
                const int gc = col0 + wc * 64 + n * 16 + csel;
                float v = acc[m][n][j];
                if (rowmask) {
                    const int b_ = gr & 3, s_ = gr >> 2;   // B_DIM == 4
                    if (rowmask[b_ * seq + s_] != 0) v = 0.f;
                }
                v += bias[gc];
                if (relu) v = fmaxf(v, 0.f);
                if (residual) v += residual[(size_t)gr * N + gc];
                const size_t oi = (size_t)gr * N + gc;
                if (out_f)  out_f[oi]  = v;
                if (out_bf) out_bf[oi] = f2b(v);
            }
        }
    }
}

// ---------------------------------------------------------------------------
// Flash attention (VALU, fp32). One WG = one (b,h) x 64 q-rows.
// 4 threads per q-row, each owns a 16-wide HD chunk. KV tiles of 64 in LDS.
// Tile-level online softmax. Q pre-scaled by 1/sqrt(HD)=0.125.
// amask: additive [T,S] f32 (or null). causal: skip tiles with s0 > t0+63.
// outc (bf16): [t, b, h*64+hd]; outp (f32, optional): [h, b, t, hd].
// ---------------------------------------------------------------------------
__global__ __launch_bounds__(256, 3) void flash_kernel(
    const float* __restrict__ Qp,
    const float* __restrict__ Kp,
    const float* __restrict__ Vp,
    const float* __restrict__ amask,
    unsigned short* __restrict__ outc,
    float* __restrict__ outp,
    int causal)
{
    __shared__ __align__(16) float Ks[64 * 64];
    __shared__ __align__(16) float Vs[64 * 64];
    __shared__ float Ps[64 * 65];

    const int tid = threadIdx.x;
    const int qi  = tid >> 2;
    const int c   = tid & 3;
    const int t0  = blockIdx.x * 64;
    const int h   = blockIdx.y & (H_NUM - 1);
    const int b   = blockIdx.y >> 4;
    const int t   = t0 + qi;

    float q[16];
    {
        const float* qptr = Qp + ((size_t)t * B_DIM + b) * D_MOD + h * 64 + c * 16;
#pragma unroll
        for (int j2 = 0; j2 < 4; ++j2) {
            const f32x4 v = *(const f32x4*)(qptr + j2 * 4);
#pragma unroll
            for (int j = 0; j < 4; ++j) q[j2 * 4 + j] = v[j] * 0.125f;
        }
    }

    float m_run = -INFINITY, l_run = 0.f;
    float ctx[16];
#pragma unroll
    for (int j = 0; j < 16; ++j) ctx[j] = 0.f;

    for (int s0 = 0; s0 < S_LEN; s0 += 64) {
        if (causal && s0 > t0 + 63) break;
        // stage K/V tile [64 s][64 hd] f32 via global_load_lds (linear dest)
#pragma unroll
        for (int j2 = 0; j2 < 4; ++j2) {
            const int eoff = j2 * 1024 + tid * 4;
            const int srow = eoff >> 6;
            const int scol = eoff & 63;
            const size_t gb = ((size_t)(s0 + srow) * B_DIM + b) * D_MOD + h * 64 + scol;
            __builtin_amdgcn_global_load_lds((const AS1 void*)(Kp + gb), (AS3 void*)(&Ks[eoff]), 16, 0, 0);
            __builtin_amdgcn_global_load_lds((const AS1 void*)(Vp + gb), (AS3 void*)(&Vs[eoff]), 16, 0, 0);
        }
        __syncthreads();

        // Phase A: scores (4-thread cooperative dot, xor-reduce over c)
        for (int s = 0; s < 64; ++s) {
            float p = 0.f;
#pragma unroll
            for (int j2 = 0; j2 < 4; ++j2) {
                const f32x4 kv = *(const f32x4*)&Ks[s * 64 + c * 16 + j2 * 4];
#pragma unroll
                for (int j = 0; j < 4; ++j) p += q[j2 * 4 + j] * kv[j];
            }
            p += __shfl_xor(p, 1);
            p += __shfl_xor(p, 2);
            if (c == 0) {
                if (amask) p += amask[(size_t)t * S_LEN + s0 + s];
                Ps[qi * 65 + s] = p;
            }
        }
        __syncthreads();

        // Phase B: tile max / exp / sum, online rescale
        float lmax = -INFINITY;
#pragma unroll
        for (int k2 = 0; k2 < 16; ++k2) lmax = fmaxf(lmax, Ps[qi * 65 + c + k2 * 4]);
        lmax = fmaxf(lmax, __shfl_xor(lmax, 1));
        lmax = fmaxf(lmax, __shfl_xor(lmax, 2));
        const float m_new = fmaxf(m_run, lmax);
        const float scale = __expf(m_run - m_new);
        float lsum = 0.f;
#pragma unroll
        for (int k2 = 0; k2 < 16; ++k2) {
            const int s = c + k2 * 4;
            const float e = __expf(Ps[qi * 65 + s] - m_new);
            Ps[qi * 65 + s] = e;
            lsum += e;
        }
        lsum += __shfl_xor(lsum, 1);
        lsum += __shfl_xor(lsum, 2);
        l_run = l_run * scale + lsum;
        m_run = m_new;
#pragma unroll
        for (int j = 0; j < 16; ++j) ctx[j] *= scale;
        __syncthreads();

        // Phase C: ctx += P @ V
        for (int s = 0; s < 64; ++s) {
            const float p = Ps[qi * 65 + s];
#pragma unroll
            for (int j2 = 0; j2 < 4; ++j2) {
                const f32x4 vv = *(const f32x4*)&Vs[s * 64 + c * 16 + j2 * 4];
#pragma unroll
                for (int j = 0; j < 4; ++j) ctx[j2 * 4 + j] += p * vv[j];
            }
        }
        __syncthreads();
    }

    const float inv = 1.f / l_run;
#pragma unroll
    for (int j = 0; j < 16; ++j) ctx[j] *= inv;

    {
        us8 o0, o1;
#pragma unroll
        for (int j = 0; j < 8; ++j) { o0[j] = f2b(ctx[j]); o1[j] = f2b(ctx[8 + j]); }
        const size_t ob = ((size_t)t * B_DIM + b) * D_MOD + h * 64 + c * 16;
        *(us8*)&outc[ob] = o0;
        *(us8*)&outc[ob + 8] = o1;
    }
    if (outp) {
        const size_t pb = (((size_t)h * B_DIM + b) * T_LEN + t) * 64 + c * 16;
#pragma unroll
        for (int j2 = 0; j2 < 4; ++j2) {
            f32x4 o;
#pragma unroll
            for (int j = 0; j < 4; ++j) o[j] = ctx[j2 * 4 + j];
            *(f32x4*)&outp[pb + j2 * 4] = o;
        }
    }
}

// ---------------------------------------------------------------------------
// LayerNorm over D=1024 (fp32 in, fp32 and/or bf16 out). One WG per row.
// ---------------------------------------------------------------------------
__global__ __launch_bounds__(256) void layernorm_kernel(
    const float* __restrict__ y,
    const float* __restrict__ g,
    const float* __restrict__ be,
    float* __restrict__ out_f,
    unsigned short* __restrict__ out_bf)
{
    __shared__ float red[8];
    const int row = blockIdx.x;
    const int tid = threadIdx.x;
    const float* yr = y + (size_t)row * D_MOD;
    const f32x4 v = *(const f32x4*)&yr[tid * 4];
    float s = v[0] + v[1] + v[2] + v[3];
#pragma unroll
    for (int o = 32; o > 0; o >>= 1) s += __shfl_xor(s, o);
    if ((tid & 63) == 0) red[tid >> 6] = s;
    __syncthreads();
    const float mu = (red[0] + red[1] + red[2] + red[3]) * (1.f / D_MOD);
    const float d0 = v[0] - mu, d1 = v[1] - mu, d2 = v[2] - mu, d3 = v[3] - mu;
    float s2 = d0 * d0 + d1 * d1 + d2 * d2 + d3 * d3;
#pragma unroll
    for (int o = 32; o > 0; o >>= 1) s2 += __shfl_xor(s2, o);
    if ((tid & 63) == 0) red[4 + (tid >> 6)] = s2;
    __syncthreads();
    const float var  = (red[4] + red[5] + red[6] + red[7]) * (1.f / D_MOD);
    const float rstd = rsqrtf(var + 1e-5f);
    const float dd[4] = {d0, d1, d2, d3};
    f32x4 of;
    us4 ob;
#pragma unroll
    for (int j = 0; j < 4; ++j) {
        const int col = tid * 4 + j;
        const float r = dd[j] * rstd * g[col] + be[col];
        of[j] = r;
        ob[j] = f2b(r);
    }
    const size_t oi = (size_t)row * D_MOD + tid * 4;
    if (out_f)  *(f32x4*)&out_f[oi] = of;
    if (out_bf) *(us4*)&out_bf[oi]  = ob;
}

// ---------------------------------------------------------------------------
extern "C" void kernel_launch(void* const* d_in, const int* in_sizes, int n_in,
                              void* d_out, int out_size, void* d_ws, size_t ws_size,
                              hipStream_t stream) {
    (void)in_sizes; (void)n_in; (void)out_size; (void)ws_size;

    const float* x0    = (const float*)d_in[0];
    const float* enc   = (const float*)d_in[1];
    const float* smask = (const float*)d_in[2];
    const int* sa_pad  = (const int*)d_in[3];
    const int* ea_pad  = (const int*)d_in[4];
    const float* sa_Wq = (const float*)d_in[5];
    const float* sa_bq = (const float*)d_in[6];
    const float* sa_Wk = (const float*)d_in[7];
    const float* sa_bk = (const float*)d_in[8];
    const float* sa_Wv = (const float*)d_in[9];
    const float* sa_bv = (const float*)d_in[10];
    const float* sa_Wo = (const float*)d_in[11];
    const float* sa_bo = (const float*)d_in[12];
    const float* ea_Wq = (const float*)d_in[13];
    const float* ea_bq = (const float*)d_in[14];
    const float* ea_Wk = (const float*)d_in[15];
    const float* ea_bk = (const float*)d_in[16];
    const float* ea_Wv = (const float*)d_in[17];
    const float* ea_bv = (const float*)d_in[18];
    const float* ea_Wo = (const float*)d_in[19];
    const float* ea_bo = (const float*)d_in[20];
    const float* ln1_g = (const float*)d_in[21];
    const float* ln1_b = (const float*)d_in[22];
    const float* ln2_g = (const float*)d_in[23];
    const float* ln2_b = (const float*)d_in[24];
    const float* ln3_g = (const float*)d_in[25];
    const float* ln3_b = (const float*)d_in[26];
    const float* fc1_W = (const float*)d_in[27];
    const float* fc1_b = (const float*)d_in[28];
    const float* fc2_W = (const float*)d_in[29];
    const float* fc2_b = (const float*)d_in[30];

    // ---- workspace layout (elements) ----
    const size_t DD = (size_t)D_MOD * D_MOD;    // 1,048,576
    const size_t FD = (size_t)FFN_D * D_MOD;    // 4,194,304
    const size_t SL = (size_t)NTOK * D_MOD;     // 4,194,304

    unsigned short* ws_us = (unsigned short*)d_ws;
    unsigned short* wb[10];
    for (int i = 0; i < 8; ++i) wb[i] = ws_us + i * DD;
    wb[8] = ws_us + 8 * DD;           // fc1_W bf16 (FD)
    wb[9] = ws_us + 8 * DD + FD;      // fc2_W bf16 (FD)
    unsigned short* abf = ws_us + 8 * DD + 2 * FD;   // x0 bf16, later X1 bf16
    unsigned short* ebf = abf + SL;                   // enc bf16, later X2 bf16
    unsigned short* Cb  = ebf + SL;                   // attn ctx bf16
    float* fbase = (float*)(Cb + SL);
    float* Qf  = fbase;            // also overlaid by Hbf (fc1 out, bf16, 2*SL el)
    float* Kf  = fbase + SL;
    float* Vf  = fbase + 2 * SL;
    float* Yf  = fbase + 3 * SL;   // pre-LN accumulator
    float* X1f = fbase + 4 * SL;   // LN1 out f32; later LN2 out (X2f)
    unsigned short* Hbf = (unsigned short*)Qf;        // [NTOK, FFN] bf16 = 2*SL el

    float* outx = (float*)d_out;       // x [T,B,D]
    float* outa = outx + SL;           // attn [H,B,T,HD]

    const dim3 blk(256);
    const dim3 g_proj(NTOK / 128, D_MOD / 128);   // (32, 8)
    const dim3 g_fc1(NTOK / 128, FFN_D / 128);    // (32, 32)
    const dim3 g_attn(T_LEN / 64, B_DIM * H_NUM); // (16, 64)
    unsigned short* nbf = nullptr;     // null bf16-out placeholder (non-const!)
    float* nff = nullptr;              // null f32-out placeholder
    const float* nf = nullptr;
    const int* ni = nullptr;

    // ---- fp32 -> bf16 conversions ----
    {
        const float* srcs[12]  = {x0, enc, sa_Wq, sa_Wk, sa_Wv, sa_Wo,
                                  ea_Wq, ea_Wk, ea_Wv, ea_Wo, fc1_W, fc2_W};
        unsigned short* dsts[12] = {abf, ebf, wb[0], wb[1], wb[2], wb[3],
                                    wb[4], wb[5], wb[6], wb[7], wb[8], wb[9]};
        const size_t cnts[12] = {SL, SL, DD, DD, DD, DD, DD, DD, DD, DD, FD, FD};
        for (int i = 0; i < 12; ++i) {
            const int n8 = (int)(cnts[i] / 8);
            const int grid = (n8 + 255) / 256 < 2048 ? (n8 + 255) / 256 : 2048;
            cvt_kernel<<<dim3(grid), blk, 0, stream>>>(srcs[i], dsts[i], n8);
        }
    }

    // ---- self-attention block ----
    gemm_bt_kernel<<<g_proj, blk, 0, stream>>>(abf, wb[0], sa_bq, nf, ni, nbf, Qf, NTOK, D_MOD, D_MOD, 0);
    gemm_bt_kernel<<<g_proj, blk, 0, stream>>>(abf, wb[1], sa_bk, nf, sa_pad, nbf, Kf, NTOK, D_MOD, D_MOD, 0);
    gemm_bt_kernel<<<g_proj, blk, 0, stream>>>(abf, wb[2], sa_bv, nf, ni, nbf, Vf, NTOK, D_MOD, D_MOD, 0);
    flash_kernel<<<g_attn, blk, 0, stream>>>(Qf, Kf, Vf, smask, Cb, nff, 1);
    gemm_bt_kernel<<<g_proj, blk, 0, stream>>>(Cb, wb[3], sa_bo, x0, ni, nbf, Yf, NTOK, D_MOD, D_MOD, 0);
    layernorm_kernel<<<dim3(NTOK), blk, 0, stream>>>(Yf, ln1_g, ln1_b, X1f, abf);

    // ---- encoder-decoder attention block ----
    gemm_bt_kernel<<<g_proj, blk, 0, stream>>>(abf, wb[4], ea_bq, nf, ni, nbf, Qf, NTOK, D_MOD, D_MOD, 0);
    gemm_bt_kernel<<<g_proj, blk, 0, stream>>>(ebf, wb[5], ea_bk, nf, ea_pad, nbf, Kf, NTOK, D_MOD, D_MOD, 0);
    gemm_bt_kernel<<<g_proj, blk, 0, stream>>>(ebf, wb[6], ea_bv, nf, ni, nbf, Vf, NTOK, D_MOD, D_MOD, 0);
    flash_kernel<<<g_attn, blk, 0, stream>>>(Qf, Kf, Vf, nf, Cb, outa, 0);
    gemm_bt_kernel<<<g_proj, blk, 0, stream>>>(Cb, wb[7], ea_bo, X1f, ni, nbf, Yf, NTOK, D_MOD, D_MOD, 0);
    layernorm_kernel<<<dim3(NTOK), blk, 0, stream>>>(Yf, ln2_g, ln2_b, X1f, ebf);  // X2f=X1f, X2bf=ebf

    // ---- FFN block ----
    gemm_bt_kernel<<<g_fc1, blk, 0, stream>>>(ebf, wb[8], fc1_b, nf, ni, Hbf, nff, NTOK, FFN_D, D_MOD, 1);
    gemm_bt_kernel<<<g_proj, blk, 0, stream>>>(Hbf, wb[9], fc2_b, X1f, ni, nbf, Yf, NTOK, D_MOD, FFN_D, 0);
    layernorm_kernel<<<dim3(NTOK), blk, 0, stream>>>(Yf, ln3_g, ln3_b, outx, nbf);
}

// Round 4
// 791.946 us; speedup vs baseline: 2.2657x; 2.2657x over previous
//
#include <hip/hip_runtime.h>
#include <hip/hip_bf16.h>

// ---------------------------------------------------------------------------
// TransformerDecoderLayer on MI355X (gfx950). fp32 I/O, bf16 MFMA GEMMs with
// fp32 accumulation, MFMA flash attention (bf16 P/V, fp32 softmax/accum).
// T=S=1024, B=4, D=1024, H=16, HD=64, FFN=4096.
// ---------------------------------------------------------------------------

typedef __attribute__((ext_vector_type(8))) short bf16x8;
typedef __attribute__((ext_vector_type(4))) float f32x4;
typedef __attribute__((ext_vector_type(8))) unsigned short us8;
typedef __attribute__((ext_vector_type(4))) unsigned short us4;

#define AS1 __attribute__((address_space(1)))
#define AS3 __attribute__((address_space(3)))

#define T_LEN 1024
#define S_LEN 1024
#define B_DIM 4
#define D_MOD 1024
#define H_NUM 16
#define FFN_D 4096
#define NTOK  4096   /* T*B rows of the token matrix */

__device__ __forceinline__ float b2f(unsigned short u) {
    return __uint_as_float(((unsigned int)u) << 16);
}
__device__ __forceinline__ unsigned short f2b(float f) {
    unsigned int x = __float_as_uint(f);
    x += 0x7fffu + ((x >> 16) & 1u);   // RNE
    return (unsigned short)(x >> 16);
}

// ---------------------------------------------------------------------------
// fp32 -> bf16 conversion, 8 elems/thread, grid-stride.
// ---------------------------------------------------------------------------
__global__ __launch_bounds__(256) void cvt_kernel(
    const float* __restrict__ in, unsigned short* __restrict__ out, int n8)
{
    int i = blockIdx.x * 256 + threadIdx.x;
    const int stride = gridDim.x * 256;
    for (; i < n8; i += stride) {
        const f32x4 a = *(const f32x4*)&in[(size_t)i * 8];
        const f32x4 b = *(const f32x4*)&in[(size_t)i * 8 + 4];
        us8 o;
#pragma unroll
        for (int j = 0; j < 4; ++j) { o[j] = f2b(a[j]); o[4 + j] = f2b(b[j]); }
        *(us8*)&out[(size_t)i * 8] = o;
    }
}

// ---------------------------------------------------------------------------
// GEMM: out[M,N] = A[M,K](bf16) @ W[N,K]^T(bf16)  + bias(f32)
//       [rowmask-zero of matmul term] [relu] [+residual(f32)]
// Writes out_f (f32) and/or out_bf (bf16), either may be null.
// ---------------------------------------------------------------------------
__global__ __launch_bounds__(256, 2) void gemm_bt_kernel(
    const unsigned short* __restrict__ A,
    const unsigned short* __restrict__ W,
    const float* __restrict__ bias,
    const float* __restrict__ residual,
    const int* __restrict__ rowmask,
    unsigned short* __restrict__ out_bf,
    float* __restrict__ out_f,
    int M, int N, int K, int relu)
{
    __shared__ __align__(16) unsigned short As[128 * 32];
    __shared__ __align__(16) unsigned short Bs[128 * 32];

    const int tid  = threadIdx.x;
    const int lane = tid & 63;
    const int wid  = tid >> 6;
    const int wr   = wid >> 1, wc = wid & 1;
    const int row0 = blockIdx.x * 128;
    const int col0 = blockIdx.y * 128;

    f32x4 acc[4][4];
#pragma unroll
    for (int m = 0; m < 4; ++m)
#pragma unroll
        for (int n = 0; n < 4; ++n)
            acc[m][n] = (f32x4){0.f, 0.f, 0.f, 0.f};

    const int arow = tid >> 2;          // 0..63
    const int acol = (tid & 3) * 8;     // element col within BK

    for (int k0 = 0; k0 < K; k0 += 32) {
#pragma unroll
        for (int j = 0; j < 2; ++j) {
            const unsigned short* srcA = A + (size_t)(row0 + j * 64 + arow) * K + k0 + acol;
            __builtin_amdgcn_global_load_lds((const AS1 void*)srcA,
                (AS3 void*)(&As[(j * 64 + arow) * 32 + acol]), 16, 0, 0);
            const unsigned short* srcB = W + (size_t)(col0 + j * 64 + arow) * K + k0 + acol;
            __builtin_amdgcn_global_load_lds((const AS1 void*)srcB,
                (AS3 void*)(&Bs[(j * 64 + arow) * 32 + acol]), 16, 0, 0);
        }
        __syncthreads();

        const int kg   = (lane >> 4) * 8;
        const int rsel = lane & 15;
        bf16x8 a[4], b[4];
#pragma unroll
        for (int m = 0; m < 4; ++m)
            a[m] = *(const bf16x8*)&As[(wr * 64 + m * 16 + rsel) * 32 + kg];
#pragma unroll
        for (int n = 0; n < 4; ++n)
            b[n] = *(const bf16x8*)&Bs[(wc * 64 + n * 16 + rsel) * 32 + kg];
#pragma unroll
        for (int m = 0; m < 4; ++m)
#pragma unroll
            for (int n = 0; n < 4; ++n)
                acc[m][n] = __builtin_amdgcn_mfma_f32_16x16x32_bf16(a[m], b[n], acc[m][n], 0, 0, 0);
        __syncthreads();
    }

    const int csel = lane & 15;
    const int rbas = (lane >> 4) * 4;
    const int seq  = M >> 2;            // M / B_DIM
#pragma unroll
    for (int m = 0; m < 4; ++m) {
#pragma unroll
        for (int n = 0; n < 4; ++n) {
#pragma unroll
            for (int j = 0; j < 4; ++j) {
                const int gr = row0 + wr * 64 + m * 16 + rbas + j;
                const int gc = col0 + wc * 64 + n * 16 + csel;
                float v = acc[m][n][j];
                if (rowmask) {
                    const int b_ = gr & 3, s_ = gr >> 2;   // B_DIM == 4
                    if (rowmask[b_ * seq + s_] != 0) v = 0.f;
                }
                v += bias[gc];
                if (relu) v = fmaxf(v, 0.f);
                if (residual) v += residual[(size_t)gr * N + gc];
                const size_t oi = (size_t)gr * N + gc;
                if (out_f)  out_f[oi]  = v;
                if (out_bf) out_bf[oi] = f2b(v);
            }
        }
    }
}

// ---------------------------------------------------------------------------
// V transpose: Vb[tok][D] (bf16) -> Vt[(b*H+h)*64+d][T] (bf16).
// One block per (t-tile of 64, bh). 64x64 tile through LDS.
// ---------------------------------------------------------------------------
__global__ __launch_bounds__(256) void vtrans_kernel(
    const unsigned short* __restrict__ Vb, unsigned short* __restrict__ Vt)
{
    __shared__ unsigned short tile[64 * 72];
    const int tid = threadIdx.x;
    const int t0  = blockIdx.x * 64;
    const int bh  = blockIdx.y;          // b*H + h
    const int h   = bh & (H_NUM - 1);
    const int b   = bh >> 4;

    const int r   = tid >> 2;            // 0..63 (t-local)
    const int c16 = (tid & 3) * 16;      // d-chunk
    const unsigned short* src = Vb + ((size_t)(t0 + r) * B_DIM + b) * D_MOD + h * 64 + c16;
    *(us8*)&tile[r * 72 + c16]     = *(const us8*)src;
    *(us8*)&tile[r * 72 + c16 + 8] = *(const us8*)(src + 8);
    __syncthreads();

    const int dr  = tid >> 2;            // 0..63 (d-local)
    const int tch = (tid & 3) * 16;      // t-chunk
    us8 o0, o1;
#pragma unroll
    for (int j = 0; j < 8; ++j) {
        o0[j] = tile[(tch + j) * 72 + dr];
        o1[j] = tile[(tch + 8 + j) * 72 + dr];
    }
    unsigned short* dst = Vt + (size_t)(bh * 64 + dr) * S_LEN + t0 + tch;
    *(us8*)dst       = o0;
    *(us8*)(dst + 8) = o1;
}

// ---------------------------------------------------------------------------
// MFMA flash attention. WG = 4 waves x 16 q-rows (QBLK=64) for one (b,h).
// KV tiles of 32 staged in LDS: K row-major [32 s][64 d], V^T [64 d][32 s],
// both XOR-swizzled via pre-swizzled global source + swizzled ds_read.
// Online softmax wave-parallel (row = 16 lanes, shfl_xor reduce). P -> bf16
// through padded per-wave LDS buffer -> PV MFMA. Causal mask analytic -1e9.
// outc bf16 [t][b][D]; outp f32 (optional) [h][b][t][64].
// ---------------------------------------------------------------------------
__global__ __launch_bounds__(256) void flash_mfma_kernel(
    const unsigned short* __restrict__ Qb,
    const unsigned short* __restrict__ Kb,
    const unsigned short* __restrict__ Vt,
    unsigned short* __restrict__ outc,
    float* __restrict__ outp,
    int causal)
{
    __shared__ __align__(16) unsigned short Ks[32 * 64];   // swizzled
    __shared__ __align__(16) unsigned short Vts[64 * 32];  // swizzled
    __shared__ __align__(16) unsigned short Ps[4 * 16 * 40];

    const int tid  = threadIdx.x;
    const int lane = tid & 63;
    const int wv   = tid >> 6;
    const int g    = lane >> 4;          // 0..3
    const int n    = lane & 15;          // 0..15
    const int t0   = blockIdx.x * 64;
    const int bh   = blockIdx.y;
    const int h    = bh & (H_NUM - 1);
    const int b    = bh >> 4;
    const int woff = wv * 16;

    // Q A-fragments (row = lane&15, k = (lane>>4)*8+j), 2 k-chunks of d
    bf16x8 qa[2];
    {
        const unsigned short* qptr =
            Qb + ((size_t)(t0 + woff + n) * B_DIM + b) * D_MOD + h * 64 + g * 8;
        qa[0] = *(const bf16x8*)qptr;
        qa[1] = *(const bf16x8*)(qptr + 32);
    }

    f32x4 ctx[4];
#pragma unroll
    for (int nt = 0; nt < 4; ++nt) ctx[nt] = (f32x4){0.f, 0.f, 0.f, 0.f};
    float m_run[4], l_run[4];
#pragma unroll
    for (int j = 0; j < 4; ++j) { m_run[j] = -INFINITY; l_run[j] = 0.f; }

    unsigned short* pw = &Ps[wv * 640];
    const int smax = causal ? (t0 + 64) : S_LEN;

    for (int s0 = 0; s0 < smax; s0 += 32) {
        // ---- stage K (4KB) and V^T (4KB), pre-swizzled global source ----
        {
            const unsigned int beta = tid * 16;
            // K: rows stride 128B, sigma = beta ^ ((row&7)<<4)
            const unsigned int lamK = beta ^ (((beta >> 7) & 7u) << 4);
            const unsigned int krow = lamK >> 7, kcolb = lamK & 127u;
            const char* srcK = (const char*)Kb +
                ((size_t)((s0 + krow) * B_DIM + b) * D_MOD + h * 64) * 2 + kcolb;
            __builtin_amdgcn_global_load_lds((const AS1 void*)srcK,
                (AS3 void*)((char*)Ks + beta), 16, 0, 0);
            // V^T: rows stride 64B, sigma = beta ^ ((row&3)<<4)
            const unsigned int lamV = beta ^ (((beta >> 6) & 3u) << 4);
            const unsigned int drow = lamV >> 6, scolb = lamV & 63u;
            const char* srcV = (const char*)Vt +
                ((size_t)(bh * 64 + drow) * S_LEN + s0) * 2 + scolb;
            __builtin_amdgcn_global_load_lds((const AS1 void*)srcV,
                (AS3 void*)((char*)Vts + beta), 16, 0, 0);
        }
        __syncthreads();

        // ---- S = Q K^T : 2 n-subtiles x 2 k-chunks ----
        f32x4 sacc[2];
        sacc[0] = (f32x4){0.f, 0.f, 0.f, 0.f};
        sacc[1] = (f32x4){0.f, 0.f, 0.f, 0.f};
#pragma unroll
        for (int u = 0; u < 2; ++u) {
#pragma unroll
            for (int kc = 0; kc < 2; ++kc) {
                const unsigned int l = (unsigned int)(u * 16 + n) * 128 + kc * 64 + g * 16;
                const unsigned int ph = l ^ ((unsigned int)(n & 7) << 4);
                const bf16x8 kb = *(const bf16x8*)((const char*)Ks + ph);
                sacc[u] = __builtin_amdgcn_mfma_f32_16x16x32_bf16(qa[kc], kb, sacc[u], 0, 0, 0);
            }
        }

        // ---- online softmax (rows = g*4+j, cols = u*16+n over 16 lanes) ----
        float e0[4], e1[4], scj[4];
#pragma unroll
        for (int j = 0; j < 4; ++j) {
            float p0 = sacc[0][j] * 0.125f;
            float p1 = sacc[1][j] * 0.125f;
            if (causal) {
                const int tq = t0 + woff + g * 4 + j;
                if (s0 + n > tq)      p0 += -1e9f;
                if (s0 + 16 + n > tq) p1 += -1e9f;
            }
            float mx = fmaxf(p0, p1);
            mx = fmaxf(mx, __shfl_xor(mx, 1));
            mx = fmaxf(mx, __shfl_xor(mx, 2));
            mx = fmaxf(mx, __shfl_xor(mx, 4));
            mx = fmaxf(mx, __shfl_xor(mx, 8));
            const float m_new = fmaxf(m_run[j], mx);
            const float sc = __expf(m_run[j] - m_new);
            m_run[j] = m_new;
            e0[j] = __expf(p0 - m_new);
            e1[j] = __expf(p1 - m_new);
            float ls = e0[j] + e1[j];
            ls += __shfl_xor(ls, 1);
            ls += __shfl_xor(ls, 2);
            ls += __shfl_xor(ls, 4);
            ls += __shfl_xor(ls, 8);
            l_run[j] = l_run[j] * sc + ls;
            scj[j] = sc;
        }
#pragma unroll
        for (int nt = 0; nt < 4; ++nt)
#pragma unroll
            for (int j = 0; j < 4; ++j) ctx[nt][j] *= scj[j];

        // ---- P (D-layout) -> bf16 LDS [16 q][40] -> A-fragment ----
#pragma unroll
        for (int j = 0; j < 4; ++j) {
            pw[(g * 4 + j) * 40 + n]      = f2b(e0[j]);
            pw[(g * 4 + j) * 40 + 16 + n] = f2b(e1[j]);
        }
        const bf16x8 pa = *(const bf16x8*)&pw[n * 40 + g * 8];

        // ---- ctx += P V : 4 d-subtiles ----
#pragma unroll
        for (int nt = 0; nt < 4; ++nt) {
            const unsigned int l = (unsigned int)(nt * 16 + n) * 64 + g * 16;
            const unsigned int ph = l ^ ((unsigned int)(n & 3) << 4);
            const bf16x8 vb = *(const bf16x8*)((const char*)Vts + ph);
            ctx[nt] = __builtin_amdgcn_mfma_f32_16x16x32_bf16(pa, vb, ctx[nt], 0, 0, 0);
        }
        __syncthreads();
    }

    // ---- epilogue ----
    float inv[4];
#pragma unroll
    for (int j = 0; j < 4; ++j) inv[j] = 1.f / l_run[j];
#pragma unroll
    for (int nt = 0; nt < 4; ++nt) {
#pragma unroll
        for (int j = 0; j < 4; ++j) {
            const int t = t0 + woff + g * 4 + j;
            const int d = nt * 16 + n;
            const float v = ctx[nt][j] * inv[j];
            outc[((size_t)t * B_DIM + b) * D_MOD + h * 64 + d] = f2b(v);
            if (outp)
                outp[((size_t)(h * B_DIM + b) * T_LEN + t) * 64 + d] = v;
        }
    }
}

// ---------------------------------------------------------------------------
// LayerNorm over D=1024 (fp32 in, fp32 and/or bf16 out). One WG per row.
// ---------------------------------------------------------------------------
__global__ __launch_bounds__(256) void layernorm_kernel(
    const float* __restrict__ y,
    const float* __restrict__ g,
    const float* __restrict__ be,
    float* __restrict__ out_f,
    unsigned short* __restrict__ out_bf)
{
    __shared__ float red[8];
    const int row = blockIdx.x;
    const int tid = threadIdx.x;
    const float* yr = y + (size_t)row * D_MOD;
    const f32x4 v = *(const f32x4*)&yr[tid * 4];
    float s = v[0] + v[1] + v[2] + v[3];
#pragma unroll
    for (int o = 32; o > 0; o >>= 1) s += __shfl_xor(s, o);
    if ((tid & 63) == 0) red[tid >> 6] = s;
    __syncthreads();
    const float mu = (red[0] + red[1] + red[2] + red[3]) * (1.f / D_MOD);
    const float d0 = v[0] - mu, d1 = v[1] - mu, d2 = v[2] - mu, d3 = v[3] - mu;
    float s2 = d0 * d0 + d1 * d1 + d2 * d2 + d3 * d3;
#pragma unroll
    for (int o = 32; o > 0; o >>= 1) s2 += __shfl_xor(s2, o);
    if ((tid & 63) == 0) red[4 + (tid >> 6)] = s2;
    __syncthreads();
    const float var  = (red[4] + red[5] + red[6] + red[7]) * (1.f / D_MOD);
    const float rstd = rsqrtf(var + 1e-5f);
    const float dd[4] = {d0, d1, d2, d3};
    f32x4 of;
    us4 ob;
#pragma unroll
    for (int j = 0; j < 4; ++j) {
        const int col = tid * 4 + j;
        const float r = dd[j] * rstd * g[col] + be[col];
        of[j] = r;
        ob[j] = f2b(r);
    }
    const size_t oi = (size_t)row * D_MOD + tid * 4;
    if (out_f)  *(f32x4*)&out_f[oi] = of;
    if (out_bf) *(us4*)&out_bf[oi]  = ob;
}

// ---------------------------------------------------------------------------
extern "C" void kernel_launch(void* const* d_in, const int* in_sizes, int n_in,
                              void* d_out, int out_size, void* d_ws, size_t ws_size,
                              hipStream_t stream) {
    (void)in_sizes; (void)n_in; (void)out_size; (void)ws_size;

    const float* x0    = (const float*)d_in[0];
    const float* enc   = (const float*)d_in[1];
    const int* sa_pad  = (const int*)d_in[3];
    const int* ea_pad  = (const int*)d_in[4];
    const float* sa_Wq = (const float*)d_in[5];
    const float* sa_bq = (const float*)d_in[6];
    const float* sa_Wk = (const float*)d_in[7];
    const float* sa_bk = (const float*)d_in[8];
    const float* sa_Wv = (const float*)d_in[9];
    const float* sa_bv = (const float*)d_in[10];
    const float* sa_Wo = (const float*)d_in[11];
    const float* sa_bo = (const float*)d_in[12];
    const float* ea_Wq = (const float*)d_in[13];
    const float* ea_bq = (const float*)d_in[14];
    const float* ea_Wk = (const float*)d_in[15];
    const float* ea_bk = (const float*)d_in[16];
    const float* ea_Wv = (const float*)d_in[17];
    const float* ea_bv = (const float*)d_in[18];
    const float* ea_Wo = (const float*)d_in[19];
    const float* ea_bo = (const float*)d_in[20];
    const float* ln1_g = (const float*)d_in[21];
    const float* ln1_b = (const float*)d_in[22];
    const float* ln2_g = (const float*)d_in[23];
    const float* ln2_b = (const float*)d_in[24];
    const float* ln3_g = (const float*)d_in[25];
    const float* ln3_b = (const float*)d_in[26];
    const float* fc1_W = (const float*)d_in[27];
    const float* fc1_b = (const float*)d_in[28];
    const float* fc2_W = (const float*)d_in[29];
    const float* fc2_b = (const float*)d_in[30];

    // ---- workspace layout (elements) ----
    const size_t DD = (size_t)D_MOD * D_MOD;    // 1,048,576
    const size_t FD = (size_t)FFN_D * D_MOD;    // 4,194,304
    const size_t SL = (size_t)NTOK * D_MOD;     // 4,194,304

    unsigned short* ws_us = (unsigned short*)d_ws;
    unsigned short* wb[10];
    for (int i = 0; i < 8; ++i) wb[i] = ws_us + i * DD;
    wb[8] = ws_us + 8 * DD;           // fc1_W bf16 (FD)
    wb[9] = ws_us + 8 * DD + FD;      // fc2_W bf16 (FD)
    unsigned short* abf = ws_us + 8 * DD + 2 * FD;   // x0 bf16, later X1 bf16
    unsigned short* ebf = abf + SL;   // enc bf16, later X2 bf16
    unsigned short* Cb  = ebf + SL;   // attn ctx bf16
    unsigned short* Qb  = Cb + SL;    // Q bf16          (Hbf overlays Qb..Vt)
    unsigned short* Kb  = Qb + SL;    // K bf16
    unsigned short* Vb  = Kb + SL;    // V bf16
    unsigned short* Vt  = Vb + SL;    // V^T bf16 [(b*H+h)*64+d][S]
    unsigned short* Hbf = Qb;         // [NTOK, FFN] bf16 = 4*SL elements
    float* fbase = (float*)(Vt + SL);
    float* Yf  = fbase;               // pre-LN accumulator (f32)
    float* X1f = fbase + SL;          // LN1/LN2 out (f32)

    float* outx = (float*)d_out;      // x [T,B,D]
    float* outa = outx + SL;          // attn [H,B,T,HD]

    const dim3 blk(256);
    const dim3 g_proj(NTOK / 128, D_MOD / 128);   // (32, 8)
    const dim3 g_fc1(NTOK / 128, FFN_D / 128);    // (32, 32)
    const dim3 g_attn(T_LEN / 64, B_DIM * H_NUM); // (16, 64)
    unsigned short* nbf = nullptr;
    float* nff = nullptr;
    const float* nf = nullptr;
    const int* ni = nullptr;

    // ---- fp32 -> bf16 conversions ----
    {
        const float* srcs[12]  = {x0, enc, sa_Wq, sa_Wk, sa_Wv, sa_Wo,
                                  ea_Wq, ea_Wk, ea_Wv, ea_Wo, fc1_W, fc2_W};
        unsigned short* dsts[12] = {abf, ebf, wb[0], wb[1], wb[2], wb[3],
                                    wb[4], wb[5], wb[6], wb[7], wb[8], wb[9]};
        const size_t cnts[12] = {SL, SL, DD, DD, DD, DD, DD, DD, DD, DD, FD, FD};
        for (int i = 0; i < 12; ++i) {
            const int n8 = (int)(cnts[i] / 8);
            const int grid = (n8 + 255) / 256 < 2048 ? (n8 + 255) / 256 : 2048;
            cvt_kernel<<<dim3(grid), blk, 0, stream>>>(srcs[i], dsts[i], n8);
        }
    }

    // ---- self-attention block ----
    gemm_bt_kernel<<<g_proj, blk, 0, stream>>>(abf, wb[0], sa_bq, nf, ni, Qb, nff, NTOK, D_MOD, D_MOD, 0);
    gemm_bt_kernel<<<g_proj, blk, 0, stream>>>(abf, wb[1], sa_bk, nf, sa_pad, Kb, nff, NTOK, D_MOD, D_MOD, 0);
    gemm_bt_kernel<<<g_proj, blk, 0, stream>>>(abf, wb[2], sa_bv, nf, ni, Vb, nff, NTOK, D_MOD, D_MOD, 0);
    vtrans_kernel<<<g_attn, blk, 0, stream>>>(Vb, Vt);
    flash_mfma_kernel<<<g_attn, blk, 0, stream>>>(Qb, Kb, Vt, Cb, nff, 1);
    gemm_bt_kernel<<<g_proj, blk, 0, stream>>>(Cb, wb[3], sa_bo, x0, ni, nbf, Yf, NTOK, D_MOD, D_MOD, 0);
    layernorm_kernel<<<dim3(NTOK), blk, 0, stream>>>(Yf, ln1_g, ln1_b, X1f, abf);

    // ---- encoder-decoder attention block ----
    gemm_bt_kernel<<<g_proj, blk, 0, stream>>>(abf, wb[4], ea_bq, nf, ni, Qb, nff, NTOK, D_MOD, D_MOD, 0);
    gemm_bt_kernel<<<g_proj, blk, 0, stream>>>(ebf, wb[5], ea_bk, nf, ea_pad, Kb, nff, NTOK, D_MOD, D_MOD, 0);
    gemm_bt_kernel<<<g_proj, blk, 0, stream>>>(ebf, wb[6], ea_bv, nf, ni, Vb, nff, NTOK, D_MOD, D_MOD, 0);
    vtrans_kernel<<<g_attn, blk, 0, stream>>>(Vb, Vt);
    flash_mfma_kernel<<<g_attn, blk, 0, stream>>>(Qb, Kb, Vt, Cb, outa, 0);
    gemm_bt_kernel<<<g_proj, blk, 0, stream>>>(Cb, wb[7], ea_bo, X1f, ni, nbf, Yf, NTOK, D_MOD, D_MOD, 0);
    layernorm_kernel<<<dim3(NTOK), blk, 0, stream>>>(Yf, ln2_g, ln2_b, X1f, ebf);  // X2f=X1f, X2bf=ebf

    // ---- FFN block ----
    gemm_bt_kernel<<<g_fc1, blk, 0, stream>>>(ebf, wb[8], fc1_b, nf, ni, Hbf, nff, NTOK, FFN_D, D_MOD, 1);
    gemm_bt_kernel<<<g_proj, blk, 0, stream>>>(Hbf, wb[9], fc2_b, X1f, ni, nbf, Yf, NTOK, D_MOD, FFN_D, 0);
    layernorm_kernel<<<dim3(NTOK), blk, 0, stream>>>(Yf, ln3_g, ln3_b, outx, nbf);
}

// Round 5
// 764.434 us; speedup vs baseline: 2.3473x; 1.0360x over previous
//
#include <hip/hip_runtime.h>
#include <hip/hip_bf16.h>

// ---------------------------------------------------------------------------
// TransformerDecoderLayer on MI355X (gfx950). fp32 I/O, bf16 MFMA GEMMs with
// fp32 accumulation, MFMA flash attention, fp32 LayerNorm.
// T=S=1024, B=4, D=1024, H=16, HD=64, FFN=4096.
// Round 5: gemm256 engine (BK=64, dbuf LDS, counted vmcnt, T2 swizzle, T5),
// QKV / KV fusion, single fused cvt. 15 launches total.
// ---------------------------------------------------------------------------

typedef __attribute__((ext_vector_type(8))) short bf16x8;
typedef __attribute__((ext_vector_type(4))) float f32x4;
typedef __attribute__((ext_vector_type(8))) unsigned short us8;
typedef __attribute__((ext_vector_type(4))) unsigned short us4;

#define AS1 __attribute__((address_space(1)))
#define AS3 __attribute__((address_space(3)))

#define T_LEN 1024
#define S_LEN 1024
#define B_DIM 4
#define D_MOD 1024
#define H_NUM 16
#define FFN_D 4096
#define NTOK  4096

__device__ __forceinline__ float b2f(unsigned short u) {
    return __uint_as_float(((unsigned int)u) << 16);
}
__device__ __forceinline__ unsigned short f2b(float f) {
    unsigned int x = __float_as_uint(f);
    x += 0x7fffu + ((x >> 16) & 1u);   // RNE
    return (unsigned short)(x >> 16);
}

// ---------------------------------------------------------------------------
// Fused fp32 -> bf16 conversion of all 12 tensors in one launch.
// Each block converts 2048 elements of one segment.
// ---------------------------------------------------------------------------
struct CvtArgs {
    const float* s[12];
    unsigned short* d[12];
};

__global__ __launch_bounds__(256) void cvt_all_kernel(CvtArgs a)
{
    const int cnt[12] = {2048, 2048, 512, 512, 512, 512, 512, 512, 512, 512, 2048, 2048};
    int bid = blockIdx.x;
    int seg = 0;
    while (bid >= cnt[seg]) { bid -= cnt[seg]; ++seg; }
    const size_t off = (size_t)bid * 2048 + threadIdx.x * 8;
    const float* src = a.s[seg] + off;
    unsigned short* dst = a.d[seg] + off;
    const f32x4 v0 = *(const f32x4*)src;
    const f32x4 v1 = *(const f32x4*)(src + 4);
    us8 o;
#pragma unroll
    for (int j = 0; j < 4; ++j) { o[j] = f2b(v0[j]); o[4 + j] = f2b(v1[j]); }
    *(us8*)dst = o;
}

// ---------------------------------------------------------------------------
// gemm256: out[M,N] = A[M,K](bf16) @ W[N,K]^T(bf16).
// 256 x BN tile (BN = 256 or 128), BK=64, 8 waves (2M x 4N), 512 threads.
// Double-buffered LDS, distance-2 K-tile prefetch, counted vmcnt (never 0 in
// steady state), raw s_barrier + explicit waitcnt asm, setprio around MFMA.
// T2 XOR swizzle: LDS linear dest + inverse-swizzled global source +
// swizzled ds_read (byte ^= (row&7)<<4; rows are 128B).
// Epilogue: per-1024-col chunk {out ptr, bias, rowmask flag}; optional relu;
// optional residual + f32 full-N output (overrides chunk bf16 outputs).
// Rows are tokens r = s*B_DIM + b; rowmask[b][s] != 0 zeroes the matmul term.
// ---------------------------------------------------------------------------
template <int BN>
__global__ __launch_bounds__(512, 2) void gemm256_kernel(
    const unsigned short* __restrict__ A,
    const unsigned short* __restrict__ W,
    const float* __restrict__ b0, const float* __restrict__ b1,
    const float* __restrict__ b2, const float* __restrict__ b3,
    const int* __restrict__ rowmask, unsigned int maskbits,
    unsigned short* __restrict__ p0, unsigned short* __restrict__ p1,
    unsigned short* __restrict__ p2, unsigned short* __restrict__ p3,
    int ostride,
    const float* __restrict__ resid, float* __restrict__ outf,
    int M, int N, int K, int relu)
{
    constexpr int WN = BN / 4;    // cols per wave
    constexpr int NR = BN / 64;   // 16-col fragments per wave

    __shared__ __align__(16) unsigned short As[2][16384];
    __shared__ __align__(16) unsigned short Bs[2][BN * 64];

    const int tid  = threadIdx.x;
    const int lane = tid & 63;
    const int wid  = tid >> 6;
    const int wr   = wid >> 2;          // 0..1
    const int wc   = wid & 3;           // 0..3
    const int row0 = blockIdx.x * 256;
    const int col0 = blockIdx.y * BN;
    const int rsel = lane & 15;
    const int kg2  = (lane >> 4) * 16;  // byte offset of k-group within 64B

    f32x4 acc[8][NR];
#pragma unroll
    for (int m = 0; m < 8; ++m)
#pragma unroll
        for (int n = 0; n < NR; ++n)
            acc[m][n] = (f32x4){0.f, 0.f, 0.f, 0.f};

    const int NT = K >> 6;

    auto stage = [&](int buf, int t) {
        const int k0 = t << 6;
#pragma unroll
        for (int i = 0; i < 4; ++i) {
            const unsigned int beta = (unsigned int)(i * 8192 + tid * 16);
            const unsigned int lam  = beta ^ (((beta >> 7) & 7u) << 4);
            const char* src = (const char*)A +
                ((size_t)(row0 + (int)(lam >> 7)) * K + k0) * 2 + (lam & 127u);
            __builtin_amdgcn_global_load_lds((const AS1 void*)src,
                (AS3 void*)((char*)&As[buf][0] + beta), 16, 0, 0);
        }
#pragma unroll
        for (int i = 0; i < NR; ++i) {
            const unsigned int beta = (unsigned int)(i * 8192 + tid * 16);
            const unsigned int lam  = beta ^ (((beta >> 7) & 7u) << 4);
            const char* src = (const char*)W +
                ((size_t)(col0 + (int)(lam >> 7)) * K + k0) * 2 + (lam & 127u);
            __builtin_amdgcn_global_load_lds((const AS1 void*)src,
                (AS3 void*)((char*)&Bs[buf][0] + beta), 16, 0, 0);
        }
    };

    auto phase = [&](int buf, int kk) {
        bf16x8 af[8];
#pragma unroll
        for (int m = 0; m < 8; ++m) {
            const int r = wr * 128 + m * 16 + rsel;
            const unsigned int l  = (unsigned int)(r * 128 + kk * 64 + kg2);
            const unsigned int ph = l ^ (((unsigned int)(r & 7)) << 4);
            af[m] = *(const bf16x8*)((const char*)&As[buf][0] + ph);
        }
        bf16x8 bfr[NR];
#pragma unroll
        for (int n = 0; n < NR; ++n) {
            const int r = wc * WN + n * 16 + rsel;
            const unsigned int l  = (unsigned int)(r * 128 + kk * 64 + kg2);
            const unsigned int ph = l ^ (((unsigned int)(r & 7)) << 4);
            bfr[n] = *(const bf16x8*)((const char*)&Bs[buf][0] + ph);
        }
        __builtin_amdgcn_s_setprio(1);
#pragma unroll
        for (int m = 0; m < 8; ++m)
#pragma unroll
            for (int n = 0; n < NR; ++n)
                acc[m][n] = __builtin_amdgcn_mfma_f32_16x16x32_bf16(af[m], bfr[n], acc[m][n], 0, 0, 0);
        __builtin_amdgcn_s_setprio(0);
    };

    // ---- prologue: stage tiles 0 and 1, wait tile 0 only ----
    stage(0, 0);
    stage(1, 1);
    if constexpr (BN == 256) { asm volatile("s_waitcnt vmcnt(8)" ::: "memory"); }
    else                     { asm volatile("s_waitcnt vmcnt(6)" ::: "memory"); }
    __builtin_amdgcn_s_barrier();
    asm volatile("" ::: "memory");

    for (int t = 0; t < NT; ++t) {
        const int cur = t & 1;
        phase(cur, 0);
        phase(cur, 1);
        // all waves done reading buf[cur] -> safe to overwrite
        asm volatile("s_waitcnt lgkmcnt(0)" ::: "memory");
        __builtin_amdgcn_s_barrier();
        asm volatile("" ::: "memory");
        if (t + 2 < NT) {
            stage(cur, t + 2);   // distance-2 prefetch into the buffer just freed
            if constexpr (BN == 256) { asm volatile("s_waitcnt vmcnt(8)" ::: "memory"); }
            else                     { asm volatile("s_waitcnt vmcnt(6)" ::: "memory"); }
        } else if (t + 1 < NT) {
            asm volatile("s_waitcnt vmcnt(0)" ::: "memory");
        }
        __builtin_amdgcn_s_barrier();
        asm volatile("" ::: "memory");
    }

    // ---- epilogue ----
    const int seq = M >> 2;
    const int c   = col0 >> 10;                  // uniform 1024-col chunk id
    unsigned short* op = c == 0 ? p0 : c == 1 ? p1 : c == 2 ? p2 : p3;
    const float*    bp = c == 0 ? b0 : c == 1 ? b1 : c == 2 ? b2 : b3;
    const bool um = rowmask && ((maskbits >> c) & 1u);
    const int rbas = (lane >> 4) * 4;
#pragma unroll
    for (int m = 0; m < 8; ++m) {
#pragma unroll
        for (int n = 0; n < NR; ++n) {
#pragma unroll
            for (int j = 0; j < 4; ++j) {
                const int gr = row0 + wr * 128 + m * 16 + rbas + j;
                const int gc = col0 + wc * WN + n * 16 + rsel;
                float v = acc[m][n][j];
                if (um && rowmask[(gr & 3) * seq + (gr >> 2)] != 0) v = 0.f;
                v += bp[gc & 1023];
                if (relu) v = fmaxf(v, 0.f);
                if (resid) v += resid[(size_t)gr * N + gc];
                if (outf) outf[(size_t)gr * N + gc] = v;
                else      op[(size_t)gr * ostride + (gc & 1023)] = f2b(v);
            }
        }
    }
}

// ---------------------------------------------------------------------------
// V transpose: Vb[tok][D] (bf16) -> Vt[(b*H+h)*64+d][T] (bf16).
// ---------------------------------------------------------------------------
__global__ __launch_bounds__(256) void vtrans_kernel(
    const unsigned short* __restrict__ Vb, unsigned short* __restrict__ Vt)
{
    __shared__ unsigned short tile[64 * 72];
    const int tid = threadIdx.x;
    const int t0  = blockIdx.x * 64;
    const int bh  = blockIdx.y;          // b*H + h
    const int h   = bh & (H_NUM - 1);
    const int b   = bh >> 4;

    const int r   = tid >> 2;            // 0..63 (t-local)
    const int c16 = (tid & 3) * 16;      // d-chunk
    const unsigned short* src = Vb + ((size_t)(t0 + r) * B_DIM + b) * D_MOD + h * 64 + c16;
    *(us8*)&tile[r * 72 + c16]     = *(const us8*)src;
    *(us8*)&tile[r * 72 + c16 + 8] = *(const us8*)(src + 8);
    __syncthreads();

    const int dr  = tid >> 2;            // 0..63 (d-local)
    const int tch = (tid & 3) * 16;      // t-chunk
    us8 o0, o1;
#pragma unroll
    for (int j = 0; j < 8; ++j) {
        o0[j] = tile[(tch + j) * 72 + dr];
        o1[j] = tile[(tch + 8 + j) * 72 + dr];
    }
    unsigned short* dst = Vt + (size_t)(bh * 64 + dr) * S_LEN + t0 + tch;
    *(us8*)dst       = o0;
    *(us8*)(dst + 8) = o1;
}

// ---------------------------------------------------------------------------
// MFMA flash attention. WG = 4 waves x 16 q-rows (QBLK=64) for one (b,h).
// ---------------------------------------------------------------------------
__global__ __launch_bounds__(256) void flash_mfma_kernel(
    const unsigned short* __restrict__ Qb,
    const unsigned short* __restrict__ Kb,
    const unsigned short* __restrict__ Vt,
    unsigned short* __restrict__ outc,
    float* __restrict__ outp,
    int causal)
{
    __shared__ __align__(16) unsigned short Ks[32 * 64];   // swizzled
    __shared__ __align__(16) unsigned short Vts[64 * 32];  // swizzled
    __shared__ __align__(16) unsigned short Ps[4 * 16 * 40];

    const int tid  = threadIdx.x;
    const int lane = tid & 63;
    const int wv   = tid >> 6;
    const int g    = lane >> 4;          // 0..3
    const int n    = lane & 15;          // 0..15
    const int t0   = blockIdx.x * 64;
    const int bh   = blockIdx.y;
    const int h    = bh & (H_NUM - 1);
    const int b    = bh >> 4;
    const int woff = wv * 16;

    bf16x8 qa[2];
    {
        const unsigned short* qptr =
            Qb + ((size_t)(t0 + woff + n) * B_DIM + b) * D_MOD + h * 64 + g * 8;
        qa[0] = *(const bf16x8*)qptr;
        qa[1] = *(const bf16x8*)(qptr + 32);
    }

    f32x4 ctx[4];
#pragma unroll
    for (int nt = 0; nt < 4; ++nt) ctx[nt] = (f32x4){0.f, 0.f, 0.f, 0.f};
    float m_run[4], l_run[4];
#pragma unroll
    for (int j = 0; j < 4; ++j) { m_run[j] = -INFINITY; l_run[j] = 0.f; }

    unsigned short* pw = &Ps[wv * 640];
    const int smax = causal ? (t0 + 64) : S_LEN;

    for (int s0 = 0; s0 < smax; s0 += 32) {
        {
            const unsigned int beta = tid * 16;
            const unsigned int lamK = beta ^ (((beta >> 7) & 7u) << 4);
            const unsigned int krow = lamK >> 7, kcolb = lamK & 127u;
            const char* srcK = (const char*)Kb +
                ((size_t)((s0 + krow) * B_DIM + b) * D_MOD + h * 64) * 2 + kcolb;
            __builtin_amdgcn_global_load_lds((const AS1 void*)srcK,
                (AS3 void*)((char*)Ks + beta), 16, 0, 0);
            const unsigned int lamV = beta ^ (((beta >> 6) & 3u) << 4);
            const unsigned int drow = lamV >> 6, scolb = lamV & 63u;
            const char* srcV = (const char*)Vt +
                ((size_t)(bh * 64 + drow) * S_LEN + s0) * 2 + scolb;
            __builtin_amdgcn_global_load_lds((const AS1 void*)srcV,
                (AS3 void*)((char*)Vts + beta), 16, 0, 0);
        }
        __syncthreads();

        f32x4 sacc[2];
        sacc[0] = (f32x4){0.f, 0.f, 0.f, 0.f};
        sacc[1] = (f32x4){0.f, 0.f, 0.f, 0.f};
#pragma unroll
        for (int u = 0; u < 2; ++u) {
#pragma unroll
            for (int kc = 0; kc < 2; ++kc) {
                const unsigned int l = (unsigned int)(u * 16 + n) * 128 + kc * 64 + g * 16;
                const unsigned int ph = l ^ ((unsigned int)(n & 7) << 4);
                const bf16x8 kb = *(const bf16x8*)((const char*)Ks + ph);
                sacc[u] = __builtin_amdgcn_mfma_f32_16x16x32_bf16(qa[kc], kb, sacc[u], 0, 0, 0);
            }
        }

        float e0[4], e1[4], scj[4];
#pragma unroll
        for (int j = 0; j < 4; ++j) {
            float p0 = sacc[0][j] * 0.125f;
            float p1 = sacc[1][j] * 0.125f;
            if (causal) {
                const int tq = t0 + woff + g * 4 + j;
                if (s0 + n > tq)      p0 += -1e9f;
                if (s0 + 16 + n > tq) p1 += -1e9f;
            }
            float mx = fmaxf(p0, p1);
            mx = fmaxf(mx, __shfl_xor(mx, 1));
            mx = fmaxf(mx, __shfl_xor(mx, 2));
            mx = fmaxf(mx, __shfl_xor(mx, 4));
            mx = fmaxf(mx, __shfl_xor(mx, 8));
            const float m_new = fmaxf(m_run[j], mx);
            const float sc = __expf(m_run[j] - m_new);
            m_run[j] = m_new;
            e0[j] = __expf(p0 - m_new);
            e1[j] = __expf(p1 - m_new);
            float ls = e0[j] + e1[j];
            ls += __shfl_xor(ls, 1);
            ls += __shfl_xor(ls, 2);
            ls += __shfl_xor(ls, 4);
            ls += __shfl_xor(ls, 8);
            l_run[j] = l_run[j] * sc + ls;
            scj[j] = sc;
        }
#pragma unroll
        for (int nt = 0; nt < 4; ++nt)
#pragma unroll
            for (int j = 0; j < 4; ++j) ctx[nt][j] *= scj[j];

#pragma unroll
        for (int j = 0; j < 4; ++j) {
            pw[(g * 4 + j) * 40 + n]      = f2b(e0[j]);
            pw[(g * 4 + j) * 40 + 16 + n] = f2b(e1[j]);
        }
        const bf16x8 pa = *(const bf16x8*)&pw[n * 40 + g * 8];

#pragma unroll
        for (int nt = 0; nt < 4; ++nt) {
            const unsigned int l = (unsigned int)(nt * 16 + n) * 64 + g * 16;
            const unsigned int ph = l ^ ((unsigned int)(n & 3) << 4);
            const bf16x8 vb = *(const bf16x8*)((const char*)Vts + ph);
            ctx[nt] = __builtin_amdgcn_mfma_f32_16x16x32_bf16(pa, vb, ctx[nt], 0, 0, 0);
        }
        __syncthreads();
    }

    float inv[4];
#pragma unroll
    for (int j = 0; j < 4; ++j) inv[j] = 1.f / l_run[j];
#pragma unroll
    for (int nt = 0; nt < 4; ++nt) {
#pragma unroll
        for (int j = 0; j < 4; ++j) {
            const int t = t0 + woff + g * 4 + j;
            const int d = nt * 16 + n;
            const float v = ctx[nt][j] * inv[j];
            outc[((size_t)t * B_DIM + b) * D_MOD + h * 64 + d] = f2b(v);
            if (outp)
                outp[((size_t)(h * B_DIM + b) * T_LEN + t) * 64 + d] = v;
        }
    }
}

// ---------------------------------------------------------------------------
// LayerNorm over D=1024 (fp32 in, fp32 and/or bf16 out). One WG per row.
// ---------------------------------------------------------------------------
__global__ __launch_bounds__(256) void layernorm_kernel(
    const float* __restrict__ y,
    const float* __restrict__ g,
    const float* __restrict__ be,
    float* __restrict__ out_f,
    unsigned short* __restrict__ out_bf)
{
    __shared__ float red[8];
    const int row = blockIdx.x;
    const int tid = threadIdx.x;
    const float* yr = y + (size_t)row * D_MOD;
    const f32x4 v = *(const f32x4*)&yr[tid * 4];
    float s = v[0] + v[1] + v[2] + v[3];
#pragma unroll
    for (int o = 32; o > 0; o >>= 1) s += __shfl_xor(s, o);
    if ((tid & 63) == 0) red[tid >> 6] = s;
    __syncthreads();
    const float mu = (red[0] + red[1] + red[2] + red[3]) * (1.f / D_MOD);
    const float d0 = v[0] - mu, d1 = v[1] - mu, d2 = v[2] - mu, d3 = v[3] - mu;
    float s2 = d0 * d0 + d1 * d1 + d2 * d2 + d3 * d3;
#pragma unroll
    for (int o = 32; o > 0; o >>= 1) s2 += __shfl_xor(s2, o);
    if ((tid & 63) == 0) red[4 + (tid >> 6)] = s2;
    __syncthreads();
    const float var  = (red[4] + red[5] + red[6] + red[7]) * (1.f / D_MOD);
    const float rstd = rsqrtf(var + 1e-5f);
    const float dd[4] = {d0, d1, d2, d3};
    f32x4 of;
    us4 ob;
#pragma unroll
    for (int j = 0; j < 4; ++j) {
        const int col = tid * 4 + j;
        const float r = dd[j] * rstd * g[col] + be[col];
        of[j] = r;
        ob[j] = f2b(r);
    }
    const size_t oi = (size_t)row * D_MOD + tid * 4;
    if (out_f)  *(f32x4*)&out_f[oi] = of;
    if (out_bf) *(us4*)&out_bf[oi]  = ob;
}

// ---------------------------------------------------------------------------
extern "C" void kernel_launch(void* const* d_in, const int* in_sizes, int n_in,
                              void* d_out, int out_size, void* d_ws, size_t ws_size,
                              hipStream_t stream) {
    (void)in_sizes; (void)n_in; (void)out_size; (void)ws_size;

    const float* x0    = (const float*)d_in[0];
    const float* enc   = (const float*)d_in[1];
    const int* sa_pad  = (const int*)d_in[3];
    const int* ea_pad  = (const int*)d_in[4];
    const float* sa_Wq = (const float*)d_in[5];
    const float* sa_bq = (const float*)d_in[6];
    const float* sa_Wk = (const float*)d_in[7];
    const float* sa_bk = (const float*)d_in[8];
    const float* sa_Wv = (const float*)d_in[9];
    const float* sa_bv = (const float*)d_in[10];
    const float* sa_Wo = (const float*)d_in[11];
    const float* sa_bo = (const float*)d_in[12];
    const float* ea_Wq = (const float*)d_in[13];
    const float* ea_bq = (const float*)d_in[14];
    const float* ea_Wk = (const float*)d_in[15];
    const float* ea_bk = (const float*)d_in[16];
    const float* ea_Wv = (const float*)d_in[17];
    const float* ea_bv = (const float*)d_in[18];
    const float* ea_Wo = (const float*)d_in[19];
    const float* ea_bo = (const float*)d_in[20];
    const float* ln1_g = (const float*)d_in[21];
    const float* ln1_b = (const float*)d_in[22];
    const float* ln2_g = (const float*)d_in[23];
    const float* ln2_b = (const float*)d_in[24];
    const float* ln3_g = (const float*)d_in[25];
    const float* ln3_b = (const float*)d_in[26];
    const float* fc1_W = (const float*)d_in[27];
    const float* fc1_b = (const float*)d_in[28];
    const float* fc2_W = (const float*)d_in[29];
    const float* fc2_b = (const float*)d_in[30];

    // ---- workspace layout (elements) ----
    const size_t DD = (size_t)D_MOD * D_MOD;    // 1,048,576
    const size_t FD = (size_t)FFN_D * D_MOD;    // 4,194,304
    const size_t SL = (size_t)NTOK * D_MOD;     // 4,194,304

    unsigned short* ws_us = (unsigned short*)d_ws;
    unsigned short* wb[10];
    for (int i = 0; i < 8; ++i) wb[i] = ws_us + i * DD;
    wb[8] = ws_us + 8 * DD;           // fc1_W bf16 (FD)
    wb[9] = ws_us + 8 * DD + FD;      // fc2_W bf16 (FD)
    unsigned short* abf = ws_us + 8 * DD + 2 * FD;   // x0 bf16, later X1 bf16
    unsigned short* ebf = abf + SL;   // enc bf16, later X2 bf16
    unsigned short* Cb  = ebf + SL;   // attn ctx bf16
    unsigned short* Qb  = Cb + SL;    // Q bf16          (Hbf overlays Qb..Vt)
    unsigned short* Kb  = Qb + SL;    // K bf16
    unsigned short* Vb  = Kb + SL;    // V bf16
    unsigned short* Vt  = Vb + SL;    // V^T bf16 [(b*H+h)*64+d][S]
    unsigned short* Hbf = Qb;         // [NTOK, FFN] bf16 = 4*SL elements
    float* fbase = (float*)(Vt + SL);
    float* Yf  = fbase;               // pre-LN accumulator (f32)
    float* X1f = fbase + SL;          // LN1/LN2 out (f32)

    float* outx = (float*)d_out;      // x [T,B,D]
    float* outa = outx + SL;          // attn [H,B,T,HD]

    const dim3 blk(256);
    const dim3 blk512(512);
    const dim3 g_attn(T_LEN / 64, B_DIM * H_NUM); // (16, 64)
    unsigned short* nbf = nullptr;
    float* nff = nullptr;
    const float* nf = nullptr;
    const int* ni = nullptr;

    // ---- fused fp32 -> bf16 conversion (1 launch, 12 segments) ----
    {
        CvtArgs ca;
        const float* srcs[12]  = {x0, enc, sa_Wq, sa_Wk, sa_Wv, sa_Wo,
                                  ea_Wq, ea_Wk, ea_Wv, ea_Wo, fc1_W, fc2_W};
        unsigned short* dsts[12] = {abf, ebf, wb[0], wb[1], wb[2], wb[3],
                                    wb[4], wb[5], wb[6], wb[7], wb[8], wb[9]};
        for (int i = 0; i < 12; ++i) { ca.s[i] = srcs[i]; ca.d[i] = dsts[i]; }
        cvt_all_kernel<<<dim3(12288), blk, 0, stream>>>(ca);
    }

    // ---- self-attention block ----
    // QKV fused: N=3072, chunks {Q,K,V}, rowmask on chunk 1 (K).
    gemm256_kernel<256><<<dim3(16, 12), blk512, 0, stream>>>(
        abf, wb[0], sa_bq, sa_bk, sa_bv, sa_bv, sa_pad, 0x2u,
        Qb, Kb, Vb, Vb, D_MOD, nf, nff, NTOK, 3072, D_MOD, 0);
    vtrans_kernel<<<g_attn, blk, 0, stream>>>(Vb, Vt);
    flash_mfma_kernel<<<g_attn, blk, 0, stream>>>(Qb, Kb, Vt, Cb, nff, 1);
    gemm256_kernel<128><<<dim3(16, 8), blk512, 0, stream>>>(
        Cb, wb[3], sa_bo, sa_bo, sa_bo, sa_bo, ni, 0u,
        Qb, Qb, Qb, Qb, D_MOD, x0, Yf, NTOK, D_MOD, D_MOD, 0);
    layernorm_kernel<<<dim3(NTOK), blk, 0, stream>>>(Yf, ln1_g, ln1_b, X1f, abf);

    // ---- encoder-decoder attention block ----
    gemm256_kernel<128><<<dim3(16, 8), blk512, 0, stream>>>(
        abf, wb[4], ea_bq, ea_bq, ea_bq, ea_bq, ni, 0u,
        Qb, Qb, Qb, Qb, D_MOD, nf, nff, NTOK, D_MOD, D_MOD, 0);
    gemm256_kernel<256><<<dim3(16, 8), blk512, 0, stream>>>(
        ebf, wb[5], ea_bk, ea_bv, ea_bv, ea_bv, ea_pad, 0x1u,
        Kb, Vb, Vb, Vb, D_MOD, nf, nff, NTOK, 2048, D_MOD, 0);
    vtrans_kernel<<<g_attn, blk, 0, stream>>>(Vb, Vt);
    flash_mfma_kernel<<<g_attn, blk, 0, stream>>>(Qb, Kb, Vt, Cb, outa, 0);
    gemm256_kernel<128><<<dim3(16, 8), blk512, 0, stream>>>(
        Cb, wb[7], ea_bo, ea_bo, ea_bo, ea_bo, ni, 0u,
        Qb, Qb, Qb, Qb, D_MOD, X1f, Yf, NTOK, D_MOD, D_MOD, 0);
    layernorm_kernel<<<dim3(NTOK), blk, 0, stream>>>(Yf, ln2_g, ln2_b, X1f, ebf);  // X2f=X1f, X2bf=ebf

    // ---- FFN block ----
    gemm256_kernel<256><<<dim3(16, 16), blk512, 0, stream>>>(
        ebf, wb[8], fc1_b, fc1_b + 1024, fc1_b + 2048, fc1_b + 3072, ni, 0u,
        Hbf, Hbf + 1024, Hbf + 2048, Hbf + 3072, FFN_D, nf, nff, NTOK, FFN_D, D_MOD, 1);
    gemm256_kernel<128><<<dim3(16, 8), blk512, 0, stream>>>(
        Hbf, wb[9], fc2_b, fc2_b, fc2_b, fc2_b, ni, 0u,
        Qb, Qb, Qb, Qb, D_MOD, X1f, Yf, NTOK, D_MOD, FFN_D, 0);
    layernorm_kernel<<<dim3(NTOK), blk, 0, stream>>>(Yf, ln3_g, ln3_b, outx, nbf);
}

// Round 6
// 703.263 us; speedup vs baseline: 2.5515x; 1.0870x over previous
//
#include <hip/hip_runtime.h>
#include <hip/hip_bf16.h>

// ---------------------------------------------------------------------------
// TransformerDecoderLayer on MI355X (gfx950). fp32 I/O, bf16 MFMA GEMMs with
// fp32 accumulation, MFMA flash attention, fp32 LayerNorm.
// Round 6: gemm8ph engine (m201-style 4-phase/K-tile interleave, counted
// vmcnt(4), T2 swizzle, T5 setprio), BN=128 grid-fill + split-K2 for N=1024.
// ---------------------------------------------------------------------------

typedef __attribute__((ext_vector_type(8))) short bf16x8;
typedef __attribute__((ext_vector_type(4))) float f32x4;
typedef __attribute__((ext_vector_type(8))) unsigned short us8;
typedef __attribute__((ext_vector_type(4))) unsigned short us4;

#define AS1 __attribute__((address_space(1)))
#define AS3 __attribute__((address_space(3)))

#define T_LEN 1024
#define S_LEN 1024
#define B_DIM 4
#define D_MOD 1024
#define H_NUM 16
#define FFN_D 4096
#define NTOK  4096

__device__ __forceinline__ float b2f(unsigned short u) {
    return __uint_as_float(((unsigned int)u) << 16);
}
__device__ __forceinline__ unsigned short f2b(float f) {
    unsigned int x = __float_as_uint(f);
    x += 0x7fffu + ((x >> 16) & 1u);   // RNE
    return (unsigned short)(x >> 16);
}

// ---------------------------------------------------------------------------
// Fused fp32 -> bf16 conversion of all 12 tensors in one launch.
// ---------------------------------------------------------------------------
struct CvtArgs {
    const float* s[12];
    unsigned short* d[12];
};

__global__ __launch_bounds__(256) void cvt_all_kernel(CvtArgs a)
{
    const int cnt[12] = {2048, 2048, 512, 512, 512, 512, 512, 512, 512, 512, 2048, 2048};
    int bid = blockIdx.x;
    int seg = 0;
    while (bid >= cnt[seg]) { bid -= cnt[seg]; ++seg; }
    const size_t off = (size_t)bid * 2048 + threadIdx.x * 8;
    const float* src = a.s[seg] + off;
    unsigned short* dst = a.d[seg] + off;
    const f32x4 v0 = *(const f32x4*)src;
    const f32x4 v1 = *(const f32x4*)(src + 4);
    us8 o;
#pragma unroll
    for (int j = 0; j < 4; ++j) { o[j] = f2b(v0[j]); o[4 + j] = f2b(v1[j]); }
    *(us8*)dst = o;
}

// ---------------------------------------------------------------------------
// gemm8ph: out[M,N] = A[M,K](bf16) @ W[N,K]^T(bf16), 256 x BN tile, BK=64,
// 8 waves (2M x 4N), 512 threads, double-buffered LDS (A 64KB + B 2*BN*128B).
// 4 phases per K-tile:
//  ph1: read A[m0..3][k0,k1](8) + B[*][k0](NR) | stage B-h0(t+1) | bar |
//       lgkm0 | prio1 | 4xNR MFMA (m0..3,k0) | prio0 | bar
//  ph2: read A[m4..7](8) + B[*][k1](NR)       | stage B-h1(t+1) | ... (m4..7,k0)
//  ph3: (no reads)                            | stage A-h0(t+2) | ... (m0..3,k1)
//  ph4: (no reads)                            | stage A-h1(t+2) | ... (m4..7,k1)
//       + s_waitcnt vmcnt(4) (counted; 0 only when draining) | bar
// T2 swizzle byte^=((row&7)<<4) via inverse-swizzled global source (rows 128B).
// Split-K: gridDim.z=ksplit; z=0 -> outf(f32)+bias(+resid); z>0 -> raw partf.
// Non-split: chunked bf16 outputs per 1024-col chunk (p0..p3/b0..b3/maskbits),
// or f32 outf(+resid) when outf != null.
// ---------------------------------------------------------------------------
template <int BN>
__global__ __launch_bounds__(512, 1) void gemm8ph_kernel(
    const unsigned short* __restrict__ A,
    const unsigned short* __restrict__ W,
    const float* __restrict__ b0, const float* __restrict__ b1,
    const float* __restrict__ b2, const float* __restrict__ b3,
    const int* __restrict__ rowmask, unsigned int maskbits,
    unsigned short* __restrict__ p0, unsigned short* __restrict__ p1,
    unsigned short* __restrict__ p2, unsigned short* __restrict__ p3,
    int ostride,
    const float* __restrict__ resid, float* __restrict__ outf,
    float* __restrict__ partf,
    int M, int N, int K, int relu, int ksplit)
{
    constexpr int NR  = BN / 64;          // B col-frags per wave (4 or 2)
    constexpr int BLH = (BN * 64) / 8192; // gload_lds per B half (2 or 1)
    constexpr int BBUF = BN * 128;        // bytes per B buffer

    __shared__ __align__(16) char ldsb[65536 + 2 * BBUF];

    const int tid  = threadIdx.x;
    const int lane = tid & 63;
    const int wid  = tid >> 6;
    const int wr   = wid >> 2;            // 0..1
    const int wc   = wid & 3;             // 0..3
    const int row0 = blockIdx.x * 256;
    const int col0 = blockIdx.y * BN;
    const int rsel = lane & 15;
    const int kg2  = (lane >> 4) * 16;    // k-group byte offset in 64B
    const int kz   = blockIdx.z;
    const int Keff = K / ksplit;
    const int koff = kz * Keff;
    const int NT   = Keff >> 6;

    f32x4 acc[8][NR];
#pragma unroll
    for (int m = 0; m < 8; ++m)
#pragma unroll
        for (int n = 0; n < NR; ++n)
            acc[m][n] = (f32x4){0.f, 0.f, 0.f, 0.f};

    auto stageA = [&](int buf, int half, int t) {
        const int k0 = koff + (t << 6);
#pragma unroll
        for (int i = 0; i < 2; ++i) {
            const unsigned int beta = (unsigned int)(half * 16384 + i * 8192 + tid * 16);
            const unsigned int lam  = beta ^ (((beta >> 7) & 7u) << 4);
            const char* src = (const char*)A +
                ((size_t)(row0 + (int)(lam >> 7)) * K + k0) * 2 + (lam & 127u);
            __builtin_amdgcn_global_load_lds((const AS1 void*)src,
                (AS3 void*)(ldsb + buf * 32768 + beta), 16, 0, 0);
        }
    };
    auto stageB = [&](int buf, int half, int t) {
        const int k0 = koff + (t << 6);
#pragma unroll
        for (int i = 0; i < BLH; ++i) {
            const unsigned int beta = (unsigned int)(half * (BN * 64) + i * 8192 + tid * 16);
            const unsigned int lam  = beta ^ (((beta >> 7) & 7u) << 4);
            const char* src = (const char*)W +
                ((size_t)(col0 + (int)(lam >> 7)) * K + k0) * 2 + (lam & 127u);
            __builtin_amdgcn_global_load_lds((const AS1 void*)src,
                (AS3 void*)(ldsb + 65536 + buf * BBUF + beta), 16, 0, 0);
        }
    };
    auto readA = [&](int buf, int m, int k) -> bf16x8 {
        const int r = wr * 128 + m * 16 + rsel;
        const unsigned int l  = (unsigned int)(r * 128 + k * 64 + kg2);
        const unsigned int ph = l ^ (((unsigned int)(r & 7)) << 4);
        return *(const bf16x8*)(ldsb + buf * 32768 + ph);
    };
    auto readB = [&](int buf, int n, int k) -> bf16x8 {
        const int r = wc * (BN / 4) + n * 16 + rsel;
        const unsigned int l  = (unsigned int)(r * 128 + k * 64 + kg2);
        const unsigned int ph = l ^ (((unsigned int)(r & 7)) << 4);
        return *(const bf16x8*)(ldsb + 65536 + buf * BBUF + ph);
    };

    // ---- prologue: tile0 (A+B), tile1 (A only; B(1) staged during tile0) ----
    stageA(0, 0, 0); stageA(0, 1, 0); stageB(0, 0, 0); stageB(0, 1, 0);
    stageA(1, 0, 1); stageA(1, 1, 1);
    asm volatile("s_waitcnt vmcnt(4)" ::: "memory");
    __builtin_amdgcn_s_barrier();

    bf16x8 Afr[8][2], Bfr[NR][2];

    for (int t = 0; t < NT; ++t) {
        const int cur = t & 1;
        // ---------------- phase 1 ----------------
#pragma unroll
        for (int m = 0; m < 4; ++m) { Afr[m][0] = readA(cur, m, 0); Afr[m][1] = readA(cur, m, 1); }
#pragma unroll
        for (int n = 0; n < NR; ++n) Bfr[n][0] = readB(cur, n, 0);
        if (t + 1 < NT) stageB(cur ^ 1, 0, t + 1);
        __builtin_amdgcn_s_barrier();
        asm volatile("s_waitcnt lgkmcnt(0)" ::: "memory");
        __builtin_amdgcn_sched_barrier(0);
        __builtin_amdgcn_s_setprio(1);
#pragma unroll
        for (int m = 0; m < 4; ++m)
#pragma unroll
            for (int n = 0; n < NR; ++n)
                acc[m][n] = __builtin_amdgcn_mfma_f32_16x16x32_bf16(Afr[m][0], Bfr[n][0], acc[m][n], 0, 0, 0);
        __builtin_amdgcn_s_setprio(0);
        __builtin_amdgcn_s_barrier();
        // ---------------- phase 2 ----------------
#pragma unroll
        for (int m = 4; m < 8; ++m) { Afr[m][0] = readA(cur, m, 0); Afr[m][1] = readA(cur, m, 1); }
#pragma unroll
        for (int n = 0; n < NR; ++n) Bfr[n][1] = readB(cur, n, 1);
        if (t + 1 < NT) stageB(cur ^ 1, 1, t + 1);
        __builtin_amdgcn_s_barrier();
        asm volatile("s_waitcnt lgkmcnt(0)" ::: "memory");
        __builtin_amdgcn_sched_barrier(0);
        __builtin_amdgcn_s_setprio(1);
#pragma unroll
        for (int m = 4; m < 8; ++m)
#pragma unroll
            for (int n = 0; n < NR; ++n)
                acc[m][n] = __builtin_amdgcn_mfma_f32_16x16x32_bf16(Afr[m][0], Bfr[n][0], acc[m][n], 0, 0, 0);
        __builtin_amdgcn_s_setprio(0);
        __builtin_amdgcn_s_barrier();
        // ---------------- phase 3 ----------------
        if (t + 2 < NT) stageA(cur, 0, t + 2);
        __builtin_amdgcn_s_barrier();
        __builtin_amdgcn_s_setprio(1);
#pragma unroll
        for (int m = 0; m < 4; ++m)
#pragma unroll
            for (int n = 0; n < NR; ++n)
                acc[m][n] = __builtin_amdgcn_mfma_f32_16x16x32_bf16(Afr[m][1], Bfr[n][1], acc[m][n], 0, 0, 0);
        __builtin_amdgcn_s_setprio(0);
        __builtin_amdgcn_s_barrier();
        // ---------------- phase 4 ----------------
        if (t + 2 < NT) stageA(cur, 1, t + 2);
        __builtin_amdgcn_s_barrier();
        __builtin_amdgcn_s_setprio(1);
#pragma unroll
        for (int m = 4; m < 8; ++m)
#pragma unroll
            for (int n = 0; n < NR; ++n)
                acc[m][n] = __builtin_amdgcn_mfma_f32_16x16x32_bf16(Afr[m][1], Bfr[n][1], acc[m][n], 0, 0, 0);
        __builtin_amdgcn_s_setprio(0);
        if (t + 2 < NT) { asm volatile("s_waitcnt vmcnt(4)" ::: "memory"); }
        else            { asm volatile("s_waitcnt vmcnt(0)" ::: "memory"); }
        __builtin_amdgcn_s_barrier();
    }

    // ---- epilogue ----
    const int seq  = M >> 2;
    const int c    = col0 >> 10;
    unsigned short* op = c == 0 ? p0 : c == 1 ? p1 : c == 2 ? p2 : p3;
    const float*    bp = c == 0 ? b0 : c == 1 ? b1 : c == 2 ? b2 : b3;
    const bool um = rowmask && ((maskbits >> c) & 1u);
    const int rbas = (lane >> 4) * 4;
    if (partf && kz > 0) {
#pragma unroll
        for (int m = 0; m < 8; ++m)
#pragma unroll
            for (int n = 0; n < NR; ++n)
#pragma unroll
                for (int j = 0; j < 4; ++j) {
                    const int gr = row0 + wr * 128 + m * 16 + rbas + j;
                    const int gc = col0 + wc * (BN / 4) + n * 16 + rsel;
                    partf[(size_t)gr * N + gc] = acc[m][n][j];
                }
    } else {
#pragma unroll
        for (int m = 0; m < 8; ++m)
#pragma unroll
            for (int n = 0; n < NR; ++n)
#pragma unroll
                for (int j = 0; j < 4; ++j) {
                    const int gr = row0 + wr * 128 + m * 16 + rbas + j;
                    const int gc = col0 + wc * (BN / 4) + n * 16 + rsel;
                    float v = acc[m][n][j];
                    if (um && rowmask[(gr & 3) * seq + (gr >> 2)] != 0) v = 0.f;
                    v += bp[gc & 1023];
                    if (relu) v = fmaxf(v, 0.f);
                    if (resid) v += resid[(size_t)gr * N + gc];
                    if (outf) outf[(size_t)gr * N + gc] = v;
                    else      op[(size_t)gr * ostride + (gc & 1023)] = f2b(v);
                }
    }
}

// ---------------------------------------------------------------------------
// V transpose: Vb[tok][D] (bf16) -> Vt[(b*H+h)*64+d][T] (bf16).
// ---------------------------------------------------------------------------
__global__ __launch_bounds__(256) void vtrans_kernel(
    const unsigned short* __restrict__ Vb, unsigned short* __restrict__ Vt)
{
    __shared__ unsigned short tile[64 * 72];
    const int tid = threadIdx.x;
    const int t0  = blockIdx.x * 64;
    const int bh  = blockIdx.y;          // b*H + h
    const int h   = bh & (H_NUM - 1);
    const int b   = bh >> 4;

    const int r   = tid >> 2;            // 0..63 (t-local)
    const int c16 = (tid & 3) * 16;      // d-chunk
    const unsigned short* src = Vb + ((size_t)(t0 + r) * B_DIM + b) * D_MOD + h * 64 + c16;
    *(us8*)&tile[r * 72 + c16]     = *(const us8*)src;
    *(us8*)&tile[r * 72 + c16 + 8] = *(const us8*)(src + 8);
    __syncthreads();

    const int dr  = tid >> 2;            // 0..63 (d-local)
    const int tch = (tid & 3) * 16;      // t-chunk
    us8 o0, o1;
#pragma unroll
    for (int j = 0; j < 8; ++j) {
        o0[j] = tile[(tch + j) * 72 + dr];
        o1[j] = tile[(tch + 8 + j) * 72 + dr];
    }
    unsigned short* dst = Vt + (size_t)(bh * 64 + dr) * S_LEN + t0 + tch;
    *(us8*)dst       = o0;
    *(us8*)(dst + 8) = o1;
}

// ---------------------------------------------------------------------------
// MFMA flash attention. WG = 4 waves x 16 q-rows (QBLK=64) for one (b,h).
// ---------------------------------------------------------------------------
__global__ __launch_bounds__(256) void flash_mfma_kernel(
    const unsigned short* __restrict__ Qb,
    const unsigned short* __restrict__ Kb,
    const unsigned short* __restrict__ Vt,
    unsigned short* __restrict__ outc,
    float* __restrict__ outp,
    int causal)
{
    __shared__ __align__(16) unsigned short Ks[32 * 64];   // swizzled
    __shared__ __align__(16) unsigned short Vts[64 * 32];  // swizzled
    __shared__ __align__(16) unsigned short Ps[4 * 16 * 40];

    const int tid  = threadIdx.x;
    const int lane = tid & 63;
    const int wv   = tid >> 6;
    const int g    = lane >> 4;          // 0..3
    const int n    = lane & 15;          // 0..15
    const int t0   = blockIdx.x * 64;
    const int bh   = blockIdx.y;
    const int h    = bh & (H_NUM - 1);
    const int b    = bh >> 4;
    const int woff = wv * 16;

    bf16x8 qa[2];
    {
        const unsigned short* qptr =
            Qb + ((size_t)(t0 + woff + n) * B_DIM + b) * D_MOD + h * 64 + g * 8;
        qa[0] = *(const bf16x8*)qptr;
        qa[1] = *(const bf16x8*)(qptr + 32);
    }

    f32x4 ctx[4];
#pragma unroll
    for (int nt = 0; nt < 4; ++nt) ctx[nt] = (f32x4){0.f, 0.f, 0.f, 0.f};
    float m_run[4], l_run[4];
#pragma unroll
    for (int j = 0; j < 4; ++j) { m_run[j] = -INFINITY; l_run[j] = 0.f; }

    unsigned short* pw = &Ps[wv * 640];
    const int smax = causal ? (t0 + 64) : S_LEN;

    for (int s0 = 0; s0 < smax; s0 += 32) {
        {
            const unsigned int beta = tid * 16;
            const unsigned int lamK = beta ^ (((beta >> 7) & 7u) << 4);
            const unsigned int krow = lamK >> 7, kcolb = lamK & 127u;
            const char* srcK = (const char*)Kb +
                ((size_t)((s0 + krow) * B_DIM + b) * D_MOD + h * 64) * 2 + kcolb;
            __builtin_amdgcn_global_load_lds((const AS1 void*)srcK,
                (AS3 void*)((char*)Ks + beta), 16, 0, 0);
            const unsigned int lamV = beta ^ (((beta >> 6) & 3u) << 4);
            const unsigned int drow = lamV >> 6, scolb = lamV & 63u;
            const char* srcV = (const char*)Vt +
                ((size_t)(bh * 64 + drow) * S_LEN + s0) * 2 + scolb;
            __builtin_amdgcn_global_load_lds((const AS1 void*)srcV,
                (AS3 void*)((char*)Vts + beta), 16, 0, 0);
        }
        __syncthreads();

        f32x4 sacc[2];
        sacc[0] = (f32x4){0.f, 0.f, 0.f, 0.f};
        sacc[1] = (f32x4){0.f, 0.f, 0.f, 0.f};
#pragma unroll
        for (int u = 0; u < 2; ++u) {
#pragma unroll
            for (int kc = 0; kc < 2; ++kc) {
                const unsigned int l = (unsigned int)(u * 16 + n) * 128 + kc * 64 + g * 16;
                const unsigned int ph = l ^ ((unsigned int)(n & 7) << 4);
                const bf16x8 kb = *(const bf16x8*)((const char*)Ks + ph);
                sacc[u] = __builtin_amdgcn_mfma_f32_16x16x32_bf16(qa[kc], kb, sacc[u], 0, 0, 0);
            }
        }

        float e0[4], e1[4], scj[4];
#pragma unroll
        for (int j = 0; j < 4; ++j) {
            float p0 = sacc[0][j] * 0.125f;
            float p1 = sacc[1][j] * 0.125f;
            if (causal) {
                const int tq = t0 + woff + g * 4 + j;
                if (s0 + n > tq)      p0 += -1e9f;
                if (s0 + 16 + n > tq) p1 += -1e9f;
            }
            float mx = fmaxf(p0, p1);
            mx = fmaxf(mx, __shfl_xor(mx, 1));
            mx = fmaxf(mx, __shfl_xor(mx, 2));
            mx = fmaxf(mx, __shfl_xor(mx, 4));
            mx = fmaxf(mx, __shfl_xor(mx, 8));
            const float m_new = fmaxf(m_run[j], mx);
            const float sc = __expf(m_run[j] - m_new);
            m_run[j] = m_new;
            e0[j] = __expf(p0 - m_new);
            e1[j] = __expf(p1 - m_new);
            float ls = e0[j] + e1[j];
            ls += __shfl_xor(ls, 1);
            ls += __shfl_xor(ls, 2);
            ls += __shfl_xor(ls, 4);
            ls += __shfl_xor(ls, 8);
            l_run[j] = l_run[j] * sc + ls;
            scj[j] = sc;
        }
#pragma unroll
        for (int nt = 0; nt < 4; ++nt)
#pragma unroll
            for (int j = 0; j < 4; ++j) ctx[nt][j] *= scj[j];

#pragma unroll
        for (int j = 0; j < 4; ++j) {
            pw[(g * 4 + j) * 40 + n]      = f2b(e0[j]);
            pw[(g * 4 + j) * 40 + 16 + n] = f2b(e1[j]);
        }
        const bf16x8 pa = *(const bf16x8*)&pw[n * 40 + g * 8];

#pragma unroll
        for (int nt = 0; nt < 4; ++nt) {
            const unsigned int l = (unsigned int)(nt * 16 + n) * 64 + g * 16;
            const unsigned int ph = l ^ ((unsigned int)(n & 3) << 4);
            const bf16x8 vb = *(const bf16x8*)((const char*)Vts + ph);
            ctx[nt] = __builtin_amdgcn_mfma_f32_16x16x32_bf16(pa, vb, ctx[nt], 0, 0, 0);
        }
        __syncthreads();
    }

    float inv[4];
#pragma unroll
    for (int j = 0; j < 4; ++j) inv[j] = 1.f / l_run[j];
#pragma unroll
    for (int nt = 0; nt < 4; ++nt) {
#pragma unroll
        for (int j = 0; j < 4; ++j) {
            const int t = t0 + woff + g * 4 + j;
            const int d = nt * 16 + n;
            const float v = ctx[nt][j] * inv[j];
            outc[((size_t)t * B_DIM + b) * D_MOD + h * 64 + d] = f2b(v);
            if (outp)
                outp[((size_t)(h * B_DIM + b) * T_LEN + t) * 64 + d] = v;
        }
    }
}

// ---------------------------------------------------------------------------
// LayerNorm over D=1024 (fp32 in + optional f32 partial, f32/bf16 out).
// ---------------------------------------------------------------------------
__global__ __launch_bounds__(256) void layernorm_kernel(
    const float* __restrict__ y,
    const float* __restrict__ part,
    const float* __restrict__ g,
    const float* __restrict__ be,
    float* __restrict__ out_f,
    unsigned short* __restrict__ out_bf)
{
    __shared__ float red[8];
    const int row = blockIdx.x;
    const int tid = threadIdx.x;
    f32x4 v = *(const f32x4*)&y[(size_t)row * D_MOD + tid * 4];
    if (part) {
        const f32x4 pv = *(const f32x4*)&part[(size_t)row * D_MOD + tid * 4];
#pragma unroll
        for (int j = 0; j < 4; ++j) v[j] += pv[j];
    }
    float s = v[0] + v[1] + v[2] + v[3];
#pragma unroll
    for (int o = 32; o > 0; o >>= 1) s += __shfl_xor(s, o);
    if ((tid & 63) == 0) red[tid >> 6] = s;
    __syncthreads();
    const float mu = (red[0] + red[1] + red[2] + red[3]) * (1.f / D_MOD);
    const float d0 = v[0] - mu, d1 = v[1] - mu, d2 = v[2] - mu, d3 = v[3] - mu;
    float s2 = d0 * d0 + d1 * d1 + d2 * d2 + d3 * d3;
#pragma unroll
    for (int o = 32; o > 0; o >>= 1) s2 += __shfl_xor(s2, o);
    if ((tid & 63) == 0) red[4 + (tid >> 6)] = s2;
    __syncthreads();
    const float var  = (red[4] + red[5] + red[6] + red[7]) * (1.f / D_MOD);
    const float rstd = rsqrtf(var + 1e-5f);
    const float dd[4] = {d0, d1, d2, d3};
    f32x4 of;
    us4 ob;
#pragma unroll
    for (int j = 0; j < 4; ++j) {
        const int col = tid * 4 + j;
        const float r = dd[j] * rstd * g[col] + be[col];
        of[j] = r;
        ob[j] = f2b(r);
    }
    const size_t oi = (size_t)row * D_MOD + tid * 4;
    if (out_f)  *(f32x4*)&out_f[oi] = of;
    if (out_bf) *(us4*)&out_bf[oi]  = ob;
}

// ---------------------------------------------------------------------------
extern "C" void kernel_launch(void* const* d_in, const int* in_sizes, int n_in,
                              void* d_out, int out_size, void* d_ws, size_t ws_size,
                              hipStream_t stream) {
    (void)in_sizes; (void)n_in; (void)out_size; (void)ws_size;

    const float* x0    = (const float*)d_in[0];
    const float* enc   = (const float*)d_in[1];
    const int* sa_pad  = (const int*)d_in[3];
    const int* ea_pad  = (const int*)d_in[4];
    const float* sa_Wq = (const float*)d_in[5];
    const float* sa_bq = (const float*)d_in[6];
    const float* sa_Wk = (const float*)d_in[7];
    const float* sa_bk = (const float*)d_in[8];
    const float* sa_Wv = (const float*)d_in[9];
    const float* sa_bv = (const float*)d_in[10];
    const float* sa_Wo = (const float*)d_in[11];
    const float* sa_bo = (const float*)d_in[12];
    const float* ea_Wq = (const float*)d_in[13];
    const float* ea_bq = (const float*)d_in[14];
    const float* ea_Wk = (const float*)d_in[15];
    const float* ea_bk = (const float*)d_in[16];
    const float* ea_Wv = (const float*)d_in[17];
    const float* ea_bv = (const float*)d_in[18];
    const float* ea_Wo = (const float*)d_in[19];
    const float* ea_bo = (const float*)d_in[20];
    const float* ln1_g = (const float*)d_in[21];
    const float* ln1_b = (const float*)d_in[22];
    const float* ln2_g = (const float*)d_in[23];
    const float* ln2_b = (const float*)d_in[24];
    const float* ln3_g = (const float*)d_in[25];
    const float* ln3_b = (const float*)d_in[26];
    const float* fc1_W = (const float*)d_in[27];
    const float* fc1_b = (const float*)d_in[28];
    const float* fc2_W = (const float*)d_in[29];
    const float* fc2_b = (const float*)d_in[30];

    // ---- workspace layout (elements) ----
    const size_t DD = (size_t)D_MOD * D_MOD;    // 1,048,576
    const size_t FD = (size_t)FFN_D * D_MOD;    // 4,194,304
    const size_t SL = (size_t)NTOK * D_MOD;     // 4,194,304

    unsigned short* ws_us = (unsigned short*)d_ws;
    unsigned short* wb[10];
    for (int i = 0; i < 8; ++i) wb[i] = ws_us + i * DD;
    wb[8] = ws_us + 8 * DD;           // fc1_W bf16 (FD)
    wb[9] = ws_us + 8 * DD + FD;      // fc2_W bf16 (FD)
    unsigned short* abf = ws_us + 8 * DD + 2 * FD;   // x0 bf16, later X1 bf16
    unsigned short* ebf = abf + SL;   // enc bf16, later X2 bf16
    unsigned short* Cb  = ebf + SL;   // attn ctx bf16
    unsigned short* Qb  = Cb + SL;    // Q bf16          (Hbf overlays Qb..Vt)
    unsigned short* Kb  = Qb + SL;    // K bf16
    unsigned short* Vb  = Kb + SL;    // V bf16
    unsigned short* Vt  = Vb + SL;    // V^T bf16 [(b*H+h)*64+d][S]
    unsigned short* Hbf = Qb;         // [NTOK, FFN] bf16 = 4*SL elements
    float* fbase = (float*)(Vt + SL);
    float* Yf  = fbase;               // pre-LN accumulator (f32)
    float* X1f = fbase + SL;          // LN1/LN2 out (f32)
    float* Pq  = (float*)Qb;          // split-K partial (16MB over Qb..Kb, dead then)
    float* Pa  = (float*)abf;         // split-K partial for fc2 (abf+ebf dead then)

    float* outx = (float*)d_out;      // x [T,B,D]
    float* outa = outx + SL;          // attn [H,B,T,HD]

    const dim3 blk(256);
    const dim3 blk512(512);
    const dim3 g_attn(T_LEN / 64, B_DIM * H_NUM); // (16, 64)
    unsigned short* nbf = nullptr;
    float* nff = nullptr;
    const float* nf = nullptr;
    const int* ni = nullptr;

    // ---- fused fp32 -> bf16 conversion (1 launch, 12 segments) ----
    {
        CvtArgs ca;
        const float* srcs[12]  = {x0, enc, sa_Wq, sa_Wk, sa_Wv, sa_Wo,
                                  ea_Wq, ea_Wk, ea_Wv, ea_Wo, fc1_W, fc2_W};
        unsigned short* dsts[12] = {abf, ebf, wb[0], wb[1], wb[2], wb[3],
                                    wb[4], wb[5], wb[6], wb[7], wb[8], wb[9]};
        for (int i = 0; i < 12; ++i) { ca.s[i] = srcs[i]; ca.d[i] = dsts[i]; }
        cvt_all_kernel<<<dim3(12288), blk, 0, stream>>>(ca);
    }

    // ---- self-attention block ----
    // QKV fused: N=3072, chunks {Q,K,V}, rowmask on chunk 1 (K).
    gemm8ph_kernel<256><<<dim3(16, 12, 1), blk512, 0, stream>>>(
        abf, wb[0], sa_bq, sa_bk, sa_bv, sa_bv, sa_pad, 0x2u,
        Qb, Kb, Vb, Vb, D_MOD, nf, nff, nff, NTOK, 3072, D_MOD, 0, 1);
    vtrans_kernel<<<g_attn, blk, 0, stream>>>(Vb, Vt);
    flash_mfma_kernel<<<g_attn, blk, 0, stream>>>(Qb, Kb, Vt, Cb, nff, 1);
    // SA out-proj: split-K2 (z0 -> Yf +bias+resid, z1 -> Pq raw)
    gemm8ph_kernel<128><<<dim3(16, 8, 2), blk512, 0, stream>>>(
        Cb, wb[3], sa_bo, sa_bo, sa_bo, sa_bo, ni, 0u,
        nbf, nbf, nbf, nbf, D_MOD, x0, Yf, Pq, NTOK, D_MOD, D_MOD, 0, 2);
    layernorm_kernel<<<dim3(NTOK), blk, 0, stream>>>(Yf, Pq, ln1_g, ln1_b, X1f, abf);

    // ---- encoder-decoder attention block ----
    gemm8ph_kernel<128><<<dim3(16, 8, 1), blk512, 0, stream>>>(
        abf, wb[4], ea_bq, ea_bq, ea_bq, ea_bq, ni, 0u,
        Qb, Qb, Qb, Qb, D_MOD, nf, nff, nff, NTOK, D_MOD, D_MOD, 0, 1);
    gemm8ph_kernel<128><<<dim3(16, 16, 1), blk512, 0, stream>>>(
        ebf, wb[5], ea_bk, ea_bv, ea_bv, ea_bv, ea_pad, 0x1u,
        Kb, Vb, Vb, Vb, D_MOD, nf, nff, nff, NTOK, 2048, D_MOD, 0, 1);
    vtrans_kernel<<<g_attn, blk, 0, stream>>>(Vb, Vt);
    flash_mfma_kernel<<<g_attn, blk, 0, stream>>>(Qb, Kb, Vt, Cb, outa, 0);
    gemm8ph_kernel<128><<<dim3(16, 8, 2), blk512, 0, stream>>>(
        Cb, wb[7], ea_bo, ea_bo, ea_bo, ea_bo, ni, 0u,
        nbf, nbf, nbf, nbf, D_MOD, X1f, Yf, Pq, NTOK, D_MOD, D_MOD, 0, 2);
    layernorm_kernel<<<dim3(NTOK), blk, 0, stream>>>(Yf, Pq, ln2_g, ln2_b, X1f, ebf);

    // ---- FFN block ----
    gemm8ph_kernel<256><<<dim3(16, 16, 1), blk512, 0, stream>>>(
        ebf, wb[8], fc1_b, fc1_b + 1024, fc1_b + 2048, fc1_b + 3072, ni, 0u,
        Hbf, Hbf + 1024, Hbf + 2048, Hbf + 3072, FFN_D, nf, nff, nff,
        NTOK, FFN_D, D_MOD, 1, 1);
    gemm8ph_kernel<128><<<dim3(16, 8, 2), blk512, 0, stream>>>(
        Hbf, wb[9], fc2_b, fc2_b, fc2_b, fc2_b, ni, 0u,
        nbf, nbf, nbf, nbf, D_MOD, X1f, Yf, Pa, NTOK, D_MOD, FFN_D, 0, 2);
    layernorm_kernel<<<dim3(NTOK), blk, 0, stream>>>(Yf, Pa, ln3_g, ln3_b, outx, nbf);
}

// Round 7
// 683.567 us; speedup vs baseline: 2.6250x; 1.0288x over previous
//
#include <hip/hip_runtime.h>
#include <hip/hip_bf16.h>

// ---------------------------------------------------------------------------
// TransformerDecoderLayer on MI355X (gfx950). fp32 I/O, bf16 MFMA GEMMs with
// fp32 accumulation, MFMA flash attention, fp32 LayerNorm.
// Round 7: flash v2 — KVBLK=64 (128B LDS rows, GEMM-proven swizzle), K/V
// double-buffer with stage-before-compute, 1 barrier/tile, diag-only causal.
// ---------------------------------------------------------------------------

typedef __attribute__((ext_vector_type(8))) short bf16x8;
typedef __attribute__((ext_vector_type(4))) float f32x4;
typedef __attribute__((ext_vector_type(8))) unsigned short us8;
typedef __attribute__((ext_vector_type(4))) unsigned short us4;

#define AS1 __attribute__((address_space(1)))
#define AS3 __attribute__((address_space(3)))

#define T_LEN 1024
#define S_LEN 1024
#define B_DIM 4
#define D_MOD 1024
#define H_NUM 16
#define FFN_D 4096
#define NTOK  4096

__device__ __forceinline__ float b2f(unsigned short u) {
    return __uint_as_float(((unsigned int)u) << 16);
}
__device__ __forceinline__ unsigned short f2b(float f) {
    unsigned int x = __float_as_uint(f);
    x += 0x7fffu + ((x >> 16) & 1u);   // RNE
    return (unsigned short)(x >> 16);
}

// ---------------------------------------------------------------------------
// Fused fp32 -> bf16 conversion of all 12 tensors in one launch.
// ---------------------------------------------------------------------------
struct CvtArgs {
    const float* s[12];
    unsigned short* d[12];
};

__global__ __launch_bounds__(256) void cvt_all_kernel(CvtArgs a)
{
    const int cnt[12] = {2048, 2048, 512, 512, 512, 512, 512, 512, 512, 512, 2048, 2048};
    int bid = blockIdx.x;
    int seg = 0;
    while (bid >= cnt[seg]) { bid -= cnt[seg]; ++seg; }
    const size_t off = (size_t)bid * 2048 + threadIdx.x * 8;
    const float* src = a.s[seg] + off;
    unsigned short* dst = a.d[seg] + off;
    const f32x4 v0 = *(const f32x4*)src;
    const f32x4 v1 = *(const f32x4*)(src + 4);
    us8 o;
#pragma unroll
    for (int j = 0; j < 4; ++j) { o[j] = f2b(v0[j]); o[4 + j] = f2b(v1[j]); }
    *(us8*)dst = o;
}

// ---------------------------------------------------------------------------
// gemm8ph: out[M,N] = A[M,K](bf16) @ W[N,K]^T(bf16), 256 x BN tile, BK=64,
// 8 waves (2M x 4N), 512 threads, double-buffered LDS, 4 phases/K-tile,
// counted vmcnt, T2 swizzle, T5 setprio. (Unchanged from round 6.)
// ---------------------------------------------------------------------------
template <int BN>
__global__ __launch_bounds__(512, 1) void gemm8ph_kernel(
    const unsigned short* __restrict__ A,
    const unsigned short* __restrict__ W,
    const float* __restrict__ b0, const float* __restrict__ b1,
    const float* __restrict__ b2, const float* __restrict__ b3,
    const int* __restrict__ rowmask, unsigned int maskbits,
    unsigned short* __restrict__ p0, unsigned short* __restrict__ p1,
    unsigned short* __restrict__ p2, unsigned short* __restrict__ p3,
    int ostride,
    const float* __restrict__ resid, float* __restrict__ outf,
    float* __restrict__ partf,
    int M, int N, int K, int relu, int ksplit)
{
    constexpr int NR  = BN / 64;          // B col-frags per wave (4 or 2)
    constexpr int BLH = (BN * 64) / 8192; // gload_lds per B half (2 or 1)
    constexpr int BBUF = BN * 128;        // bytes per B buffer

    __shared__ __align__(16) char ldsb[65536 + 2 * BBUF];

    const int tid  = threadIdx.x;
    const int lane = tid & 63;
    const int wid  = tid >> 6;
    const int wr   = wid >> 2;            // 0..1
    const int wc   = wid & 3;             // 0..3
    const int row0 = blockIdx.x * 256;
    const int col0 = blockIdx.y * BN;
    const int rsel = lane & 15;
    const int kg2  = (lane >> 4) * 16;    // k-group byte offset in 64B
    const int kz   = blockIdx.z;
    const int Keff = K / ksplit;
    const int koff = kz * Keff;
    const int NT   = Keff >> 6;

    f32x4 acc[8][NR];
#pragma unroll
    for (int m = 0; m < 8; ++m)
#pragma unroll
        for (int n = 0; n < NR; ++n)
            acc[m][n] = (f32x4){0.f, 0.f, 0.f, 0.f};

    auto stageA = [&](int buf, int half, int t) {
        const int k0 = koff + (t << 6);
#pragma unroll
        for (int i = 0; i < 2; ++i) {
            const unsigned int beta = (unsigned int)(half * 16384 + i * 8192 + tid * 16);
            const unsigned int lam  = beta ^ (((beta >> 7) & 7u) << 4);
            const char* src = (const char*)A +
                ((size_t)(row0 + (int)(lam >> 7)) * K + k0) * 2 + (lam & 127u);
            __builtin_amdgcn_global_load_lds((const AS1 void*)src,
                (AS3 void*)(ldsb + buf * 32768 + beta), 16, 0, 0);
        }
    };
    auto stageB = [&](int buf, int half, int t) {
        const int k0 = koff + (t << 6);
#pragma unroll
        for (int i = 0; i < BLH; ++i) {
            const unsigned int beta = (unsigned int)(half * (BN * 64) + i * 8192 + tid * 16);
            const unsigned int lam  = beta ^ (((beta >> 7) & 7u) << 4);
            const char* src = (const char*)W +
                ((size_t)(col0 + (int)(lam >> 7)) * K + k0) * 2 + (lam & 127u);
            __builtin_amdgcn_global_load_lds((const AS1 void*)src,
                (AS3 void*)(ldsb + 65536 + buf * BBUF + beta), 16, 0, 0);
        }
    };
    auto readA = [&](int buf, int m, int k) -> bf16x8 {
        const int r = wr * 128 + m * 16 + rsel;
        const unsigned int l  = (unsigned int)(r * 128 + k * 64 + kg2);
        const unsigned int ph = l ^ (((unsigned int)(r & 7)) << 4);
        return *(const bf16x8*)(ldsb + buf * 32768 + ph);
    };
    auto readB = [&](int buf, int n, int k) -> bf16x8 {
        const int r = wc * (BN / 4) + n * 16 + rsel;
        const unsigned int l  = (unsigned int)(r * 128 + k * 64 + kg2);
        const unsigned int ph = l ^ (((unsigned int)(r & 7)) << 4);
        return *(const bf16x8*)(ldsb + 65536 + buf * BBUF + ph);
    };

    // ---- prologue: tile0 (A+B), tile1 (A only; B(1) staged during tile0) ----
    stageA(0, 0, 0); stageA(0, 1, 0); stageB(0, 0, 0); stageB(0, 1, 0);
    stageA(1, 0, 1); stageA(1, 1, 1);
    asm volatile("s_waitcnt vmcnt(4)" ::: "memory");
    __builtin_amdgcn_s_barrier();

    bf16x8 Afr[8][2], Bfr[NR][2];

    for (int t = 0; t < NT; ++t) {
        const int cur = t & 1;
        // ---------------- phase 1 ----------------
#pragma unroll
        for (int m = 0; m < 4; ++m) { Afr[m][0] = readA(cur, m, 0); Afr[m][1] = readA(cur, m, 1); }
#pragma unroll
        for (int n = 0; n < NR; ++n) Bfr[n][0] = readB(cur, n, 0);
        if (t + 1 < NT) stageB(cur ^ 1, 0, t + 1);
        __builtin_amdgcn_s_barrier();
        asm volatile("s_waitcnt lgkmcnt(0)" ::: "memory");
        __builtin_amdgcn_sched_barrier(0);
        __builtin_amdgcn_s_setprio(1);
#pragma unroll
        for (int m = 0; m < 4; ++m)
#pragma unroll
            for (int n = 0; n < NR; ++n)
                acc[m][n] = __builtin_amdgcn_mfma_f32_16x16x32_bf16(Afr[m][0], Bfr[n][0], acc[m][n], 0, 0, 0);
        __builtin_amdgcn_s_setprio(0);
        __builtin_amdgcn_s_barrier();
        // ---------------- phase 2 ----------------
#pragma unroll
        for (int m = 4; m < 8; ++m) { Afr[m][0] = readA(cur, m, 0); Afr[m][1] = readA(cur, m, 1); }
#pragma unroll
        for (int n = 0; n < NR; ++n) Bfr[n][1] = readB(cur, n, 1);
        if (t + 1 < NT) stageB(cur ^ 1, 1, t + 1);
        __builtin_amdgcn_s_barrier();
        asm volatile("s_waitcnt lgkmcnt(0)" ::: "memory");
        __builtin_amdgcn_sched_barrier(0);
        __builtin_amdgcn_s_setprio(1);
#pragma unroll
        for (int m = 4; m < 8; ++m)
#pragma unroll
            for (int n = 0; n < NR; ++n)
                acc[m][n] = __builtin_amdgcn_mfma_f32_16x16x32_bf16(Afr[m][0], Bfr[n][0], acc[m][n], 0, 0, 0);
        __builtin_amdgcn_s_setprio(0);
        __builtin_amdgcn_s_barrier();
        // ---------------- phase 3 ----------------
        if (t + 2 < NT) stageA(cur, 0, t + 2);
        __builtin_amdgcn_s_barrier();
        __builtin_amdgcn_s_setprio(1);
#pragma unroll
        for (int m = 0; m < 4; ++m)
#pragma unroll
            for (int n = 0; n < NR; ++n)
                acc[m][n] = __builtin_amdgcn_mfma_f32_16x16x32_bf16(Afr[m][1], Bfr[n][1], acc[m][n], 0, 0, 0);
        __builtin_amdgcn_s_setprio(0);
        __builtin_amdgcn_s_barrier();
        // ---------------- phase 4 ----------------
        if (t + 2 < NT) stageA(cur, 1, t + 2);
        __builtin_amdgcn_s_barrier();
        __builtin_amdgcn_s_setprio(1);
#pragma unroll
        for (int m = 4; m < 8; ++m)
#pragma unroll
            for (int n = 0; n < NR; ++n)
                acc[m][n] = __builtin_amdgcn_mfma_f32_16x16x32_bf16(Afr[m][1], Bfr[n][1], acc[m][n], 0, 0, 0);
        __builtin_amdgcn_s_setprio(0);
        if (t + 2 < NT) { asm volatile("s_waitcnt vmcnt(4)" ::: "memory"); }
        else            { asm volatile("s_waitcnt vmcnt(0)" ::: "memory"); }
        __builtin_amdgcn_s_barrier();
    }

    // ---- epilogue ----
    const int seq  = M >> 2;
    const int c    = col0 >> 10;
    unsigned short* op = c == 0 ? p0 : c == 1 ? p1 : c == 2 ? p2 : p3;
    const float*    bp = c == 0 ? b0 : c == 1 ? b1 : c == 2 ? b2 : b3;
    const bool um = rowmask && ((maskbits >> c) & 1u);
    const int rbas = (lane >> 4) * 4;
    if (partf && kz > 0) {
#pragma unroll
        for (int m = 0; m < 8; ++m)
#pragma unroll
            for (int n = 0; n < NR; ++n)
#pragma unroll
                for (int j = 0; j < 4; ++j) {
                    const int gr = row0 + wr * 128 + m * 16 + rbas + j;
                    const int gc = col0 + wc * (BN / 4) + n * 16 + rsel;
                    partf[(size_t)gr * N + gc] = acc[m][n][j];
                }
    } else {
#pragma unroll
        for (int m = 0; m < 8; ++m)
#pragma unroll
            for (int n = 0; n < NR; ++n)
#pragma unroll
                for (int j = 0; j < 4; ++j) {
                    const int gr = row0 + wr * 128 + m * 16 + rbas + j;
                    const int gc = col0 + wc * (BN / 4) + n * 16 + rsel;
                    float v = acc[m][n][j];
                    if (um && rowmask[(gr & 3) * seq + (gr >> 2)] != 0) v = 0.f;
                    v += bp[gc & 1023];
                    if (relu) v = fmaxf(v, 0.f);
                    if (resid) v += resid[(size_t)gr * N + gc];
                    if (outf) outf[(size_t)gr * N + gc] = v;
                    else      op[(size_t)gr * ostride + (gc & 1023)] = f2b(v);
                }
    }
}

// ---------------------------------------------------------------------------
// V transpose: Vb[tok][D] (bf16) -> Vt[(b*H+h)*64+d][T] (bf16).
// ---------------------------------------------------------------------------
__global__ __launch_bounds__(256) void vtrans_kernel(
    const unsigned short* __restrict__ Vb, unsigned short* __restrict__ Vt)
{
    __shared__ unsigned short tile[64 * 72];
    const int tid = threadIdx.x;
    const int t0  = blockIdx.x * 64;
    const int bh  = blockIdx.y;          // b*H + h
    const int h   = bh & (H_NUM - 1);
    const int b   = bh >> 4;

    const int r   = tid >> 2;            // 0..63 (t-local)
    const int c16 = (tid & 3) * 16;      // d-chunk
    const unsigned short* src = Vb + ((size_t)(t0 + r) * B_DIM + b) * D_MOD + h * 64 + c16;
    *(us8*)&tile[r * 72 + c16]     = *(const us8*)src;
    *(us8*)&tile[r * 72 + c16 + 8] = *(const us8*)(src + 8);
    __syncthreads();

    const int dr  = tid >> 2;            // 0..63 (d-local)
    const int tch = (tid & 3) * 16;      // t-chunk
    us8 o0, o1;
#pragma unroll
    for (int j = 0; j < 8; ++j) {
        o0[j] = tile[(tch + j) * 72 + dr];
        o1[j] = tile[(tch + 8 + j) * 72 + dr];
    }
    unsigned short* dst = Vt + (size_t)(bh * 64 + dr) * S_LEN + t0 + tch;
    *(us8*)dst       = o0;
    *(us8*)(dst + 8) = o1;
}

// ---------------------------------------------------------------------------
// MFMA flash attention v2. WG = 4 waves x 16 q-rows (QBLK=64) for one (b,h).
// KVBLK=64: K [64 s][64 d] and V^T [64 d][64 s] tiles, both 128B rows with
// the GEMM-proven XOR swizzle (byte ^= (row&7)<<4), double-buffered with
// stage-before-compute, one barrier per tile. Softmax wave-parallel with
// 4-way local reduce before the shfl chains; diag-only causal masking.
// outc bf16 [t][b][D]; outp f32 (optional) [h][b][t][64].
// ---------------------------------------------------------------------------
__global__ __launch_bounds__(256, 3) void flash_mfma_kernel(
    const unsigned short* __restrict__ Qb,
    const unsigned short* __restrict__ Kb,
    const unsigned short* __restrict__ Vt,
    unsigned short* __restrict__ outc,
    float* __restrict__ outp,
    int causal)
{
    __shared__ __align__(16) unsigned short Ks[2][64 * 64];   // swizzled, 8KB x2
    __shared__ __align__(16) unsigned short Vts[2][64 * 64];  // swizzled, 8KB x2
    __shared__ __align__(16) unsigned short Ps[4][16 * 72];   // per-wave P, 72-pad

    const int tid  = threadIdx.x;
    const int lane = tid & 63;
    const int wv   = tid >> 6;
    const int g    = lane >> 4;          // 0..3
    const int n    = lane & 15;          // 0..15
    const int t0   = blockIdx.x * 64;
    const int bh   = blockIdx.y;
    const int h    = bh & (H_NUM - 1);
    const int b    = bh >> 4;
    const int woff = wv * 16;

    // Q A-fragments (row = lane&15, k = (lane>>4)*8+j), 2 k-chunks of d
    bf16x8 qa[2];
    {
        const unsigned short* qptr =
            Qb + ((size_t)(t0 + woff + n) * B_DIM + b) * D_MOD + h * 64 + g * 8;
        qa[0] = *(const bf16x8*)qptr;
        qa[1] = *(const bf16x8*)(qptr + 32);
    }

    f32x4 ctx[4];
#pragma unroll
    for (int nt = 0; nt < 4; ++nt) ctx[nt] = (f32x4){0.f, 0.f, 0.f, 0.f};
    float m_run[4], l_run[4];
#pragma unroll
    for (int j = 0; j < 4; ++j) { m_run[j] = -INFINITY; l_run[j] = 0.f; }

    unsigned short* pw = &Ps[wv][0];
    const int smax = causal ? (t0 + 64) : S_LEN;
    const int NTt  = smax >> 6;

    auto stage = [&](int buf, int s0) {
#pragma unroll
        for (int i = 0; i < 2; ++i) {
            const unsigned int beta = (unsigned int)(i * 4096 + tid * 16);
            const unsigned int lam  = beta ^ (((beta >> 7) & 7u) << 4);
            const int row = (int)(lam >> 7);           // 0..63
            const unsigned int colb = lam & 127u;
            const char* srcK = (const char*)Kb +
                ((size_t)((s0 + row) * B_DIM + b) * D_MOD + h * 64) * 2 + colb;
            __builtin_amdgcn_global_load_lds((const AS1 void*)srcK,
                (AS3 void*)((char*)&Ks[buf][0] + beta), 16, 0, 0);
            const char* srcV = (const char*)Vt +
                ((size_t)(bh * 64 + row) * S_LEN + s0) * 2 + colb;
            __builtin_amdgcn_global_load_lds((const AS1 void*)srcV,
                (AS3 void*)((char*)&Vts[buf][0] + beta), 16, 0, 0);
        }
    };

    stage(0, 0);
    for (int t = 0; t < NTt; ++t) {
        const int s0  = t << 6;
        const int cur = t & 1;
        asm volatile("s_waitcnt vmcnt(0)" ::: "memory");
        __builtin_amdgcn_s_barrier();
        if (t + 1 < NTt) stage(cur ^ 1, s0 + 64);

        // ---- S = Q K^T : 4 col-subtiles x 2 k-chunks ----
        f32x4 sacc[4];
#pragma unroll
        for (int u = 0; u < 4; ++u) sacc[u] = (f32x4){0.f, 0.f, 0.f, 0.f};
#pragma unroll
        for (int u = 0; u < 4; ++u) {
#pragma unroll
            for (int kc = 0; kc < 2; ++kc) {
                const int r = u * 16 + n;
                const unsigned int l  = (unsigned int)(r * 128 + kc * 64 + g * 16);
                const unsigned int ph = l ^ (((unsigned int)(r & 7)) << 4);
                const bf16x8 kb = *(const bf16x8*)((const char*)&Ks[cur][0] + ph);
                sacc[u] = __builtin_amdgcn_mfma_f32_16x16x32_bf16(qa[kc], kb, sacc[u], 0, 0, 0);
            }
        }

        // ---- online softmax (rows = g*4+j; 16 lanes x 4 local cols) ----
        const bool diag = causal && (s0 + 64 > t0);
        float scj[4];
#pragma unroll
        for (int j = 0; j < 4; ++j) {
            float p[4];
#pragma unroll
            for (int u = 0; u < 4; ++u) p[u] = sacc[u][j] * 0.125f;
            if (diag) {
                const int tq = t0 + woff + g * 4 + j;
#pragma unroll
                for (int u = 0; u < 4; ++u)
                    if (s0 + u * 16 + n > tq) p[u] += -1e9f;
            }
            float pm = fmaxf(fmaxf(p[0], p[1]), fmaxf(p[2], p[3]));
            pm = fmaxf(pm, __shfl_xor(pm, 1));
            pm = fmaxf(pm, __shfl_xor(pm, 2));
            pm = fmaxf(pm, __shfl_xor(pm, 4));
            pm = fmaxf(pm, __shfl_xor(pm, 8));
            const float m_new = fmaxf(m_run[j], pm);
            const float sc = __expf(m_run[j] - m_new);
            m_run[j] = m_new;
            float e[4];
#pragma unroll
            for (int u = 0; u < 4; ++u) e[u] = __expf(p[u] - m_new);
            float ls = (e[0] + e[1]) + (e[2] + e[3]);
            ls += __shfl_xor(ls, 1);
            ls += __shfl_xor(ls, 2);
            ls += __shfl_xor(ls, 4);
            ls += __shfl_xor(ls, 8);
            l_run[j] = l_run[j] * sc + ls;
            scj[j] = sc;
            // write P row (g*4+j), cols u*16+n
#pragma unroll
            for (int u = 0; u < 4; ++u)
                pw[(g * 4 + j) * 72 + u * 16 + n] = f2b(e[u]);
        }
#pragma unroll
        for (int nt = 0; nt < 4; ++nt)
#pragma unroll
            for (int j = 0; j < 4; ++j) ctx[nt][j] *= scj[j];

        // ---- ctx += P V : A-frag from P LDS, B-frag from V^T ----
        bf16x8 pa[2];
#pragma unroll
        for (int ks = 0; ks < 2; ++ks)
            pa[ks] = *(const bf16x8*)&pw[n * 72 + ks * 32 + g * 8];
#pragma unroll
        for (int nt = 0; nt < 4; ++nt) {
#pragma unroll
            for (int ks = 0; ks < 2; ++ks) {
                const int r = nt * 16 + n;
                const unsigned int l  = (unsigned int)(r * 128 + ks * 64 + g * 16);
                const unsigned int ph = l ^ (((unsigned int)(r & 7)) << 4);
                const bf16x8 vb = *(const bf16x8*)((const char*)&Vts[cur][0] + ph);
                ctx[nt] = __builtin_amdgcn_mfma_f32_16x16x32_bf16(pa[ks], vb, ctx[nt], 0, 0, 0);
            }
        }
    }

    // ---- epilogue ----
    float inv[4];
#pragma unroll
    for (int j = 0; j < 4; ++j) inv[j] = 1.f / l_run[j];
#pragma unroll
    for (int nt = 0; nt < 4; ++nt) {
#pragma unroll
        for (int j = 0; j < 4; ++j) {
            const int t = t0 + woff + g * 4 + j;
            const int d = nt * 16 + n;
            const float v = ctx[nt][j] * inv[j];
            outc[((size_t)t * B_DIM + b) * D_MOD + h * 64 + d] = f2b(v);
            if (outp)
                outp[((size_t)(h * B_DIM + b) * T_LEN + t) * 64 + d] = v;
        }
    }
}

// ---------------------------------------------------------------------------
// LayerNorm over D=1024 (fp32 in + optional f32 partial, f32/bf16 out).
// ---------------------------------------------------------------------------
__global__ __launch_bounds__(256) void layernorm_kernel(
    const float* __restrict__ y,
    const float* __restrict__ part,
    const float* __restrict__ g,
    const float* __restrict__ be,
    float* __restrict__ out_f,
    unsigned short* __restrict__ out_bf)
{
    __shared__ float red[8];
    const int row = blockIdx.x;
    const int tid = threadIdx.x;
    f32x4 v = *(const f32x4*)&y[(size_t)row * D_MOD + tid * 4];
    if (part) {
        const f32x4 pv = *(const f32x4*)&part[(size_t)row * D_MOD + tid * 4];
#pragma unroll
        for (int j = 0; j < 4; ++j) v[j] += pv[j];
    }
    float s = v[0] + v[1] + v[2] + v[3];
#pragma unroll
    for (int o = 32; o > 0; o >>= 1) s += __shfl_xor(s, o);
    if ((tid & 63) == 0) red[tid >> 6] = s;
    __syncthreads();
    const float mu = (red[0] + red[1] + red[2] + red[3]) * (1.f / D_MOD);
    const float d0 = v[0] - mu, d1 = v[1] - mu, d2 = v[2] - mu, d3 = v[3] - mu;
    float s2 = d0 * d0 + d1 * d1 + d2 * d2 + d3 * d3;
#pragma unroll
    for (int o = 32; o > 0; o >>= 1) s2 += __shfl_xor(s2, o);
    if ((tid & 63) == 0) red[4 + (tid >> 6)] = s2;
    __syncthreads();
    const float var  = (red[4] + red[5] + red[6] + red[7]) * (1.f / D_MOD);
    const float rstd = rsqrtf(var + 1e-5f);
    const float dd[4] = {d0, d1, d2, d3};
    f32x4 of;
    us4 ob;
#pragma unroll
    for (int j = 0; j < 4; ++j) {
        const int col = tid * 4 + j;
        const float r = dd[j] * rstd * g[col] + be[col];
        of[j] = r;
        ob[j] = f2b(r);
    }
    const size_t oi = (size_t)row * D_MOD + tid * 4;
    if (out_f)  *(f32x4*)&out_f[oi] = of;
    if (out_bf) *(us4*)&out_bf[oi]  = ob;
}

// ---------------------------------------------------------------------------
extern "C" void kernel_launch(void* const* d_in, const int* in_sizes, int n_in,
                              void* d_out, int out_size, void* d_ws, size_t ws_size,
                              hipStream_t stream) {
    (void)in_sizes; (void)n_in; (void)out_size; (void)ws_size;

    const float* x0    = (const float*)d_in[0];
    const float* enc   = (const float*)d_in[1];
    const int* sa_pad  = (const int*)d_in[3];
    const int* ea_pad  = (const int*)d_in[4];
    const float* sa_Wq = (const float*)d_in[5];
    const float* sa_bq = (const float*)d_in[6];
    const float* sa_Wk = (const float*)d_in[7];
    const float* sa_bk = (const float*)d_in[8];
    const float* sa_Wv = (const float*)d_in[9];
    const float* sa_bv = (const float*)d_in[10];
    const float* sa_Wo = (const float*)d_in[11];
    const float* sa_bo = (const float*)d_in[12];
    const float* ea_Wq = (const float*)d_in[13];
    const float* ea_bq = (const float*)d_in[14];
    const float* ea_Wk = (const float*)d_in[15];
    const float* ea_bk = (const float*)d_in[16];
    const float* ea_Wv = (const float*)d_in[17];
    const float* ea_bv = (const float*)d_in[18];
    const float* ea_Wo = (const float*)d_in[19];
    const float* ea_bo = (const float*)d_in[20];
    const float* ln1_g = (const float*)d_in[21];
    const float* ln1_b = (const float*)d_in[22];
    const float* ln2_g = (const float*)d_in[23];
    const float* ln2_b = (const float*)d_in[24];
    const float* ln3_g = (const float*)d_in[25];
    const float* ln3_b = (const float*)d_in[26];
    const float* fc1_W = (const float*)d_in[27];
    const float* fc1_b = (const float*)d_in[28];
    const float* fc2_W = (const float*)d_in[29];
    const float* fc2_b = (const float*)d_in[30];

    // ---- workspace layout (elements) ----
    const size_t DD = (size_t)D_MOD * D_MOD;    // 1,048,576
    const size_t FD = (size_t)FFN_D * D_MOD;    // 4,194,304
    const size_t SL = (size_t)NTOK * D_MOD;     // 4,194,304

    unsigned short* ws_us = (unsigned short*)d_ws;
    unsigned short* wb[10];
    for (int i = 0; i < 8; ++i) wb[i] = ws_us + i * DD;
    wb[8] = ws_us + 8 * DD;           // fc1_W bf16 (FD)
    wb[9] = ws_us + 8 * DD + FD;      // fc2_W bf16 (FD)
    unsigned short* abf = ws_us + 8 * DD + 2 * FD;   // x0 bf16, later X1 bf16
    unsigned short* ebf = abf + SL;   // enc bf16, later X2 bf16
    unsigned short* Cb  = ebf + SL;   // attn ctx bf16
    unsigned short* Qb  = Cb + SL;    // Q bf16          (Hbf overlays Qb..Vt)
    unsigned short* Kb  = Qb + SL;    // K bf16
    unsigned short* Vb  = Kb + SL;    // V bf16
    unsigned short* Vt  = Vb + SL;    // V^T bf16 [(b*H+h)*64+d][S]
    unsigned short* Hbf = Qb;         // [NTOK, FFN] bf16 = 4*SL elements
    float* fbase = (float*)(Vt + SL);
    float* Yf  = fbase;               // pre-LN accumulator (f32)
    float* X1f = fbase + SL;          // LN1/LN2 out (f32)
    float* Pq  = (float*)Qb;          // split-K partial (16MB over Qb..Kb, dead then)
    float* Pa  = (float*)abf;         // split-K partial for fc2 (abf+ebf dead then)

    float* outx = (float*)d_out;      // x [T,B,D]
    float* outa = outx + SL;          // attn [H,B,T,HD]

    const dim3 blk(256);
    const dim3 blk512(512);
    const dim3 g_attn(T_LEN / 64, B_DIM * H_NUM); // (16, 64)
    unsigned short* nbf = nullptr;
    float* nff = nullptr;
    const float* nf = nullptr;
    const int* ni = nullptr;

    // ---- fused fp32 -> bf16 conversion (1 launch, 12 segments) ----
    {
        CvtArgs ca;
        const float* srcs[12]  = {x0, enc, sa_Wq, sa_Wk, sa_Wv, sa_Wo,
                                  ea_Wq, ea_Wk, ea_Wv, ea_Wo, fc1_W, fc2_W};
        unsigned short* dsts[12] = {abf, ebf, wb[0], wb[1], wb[2], wb[3],
                                    wb[4], wb[5], wb[6], wb[7], wb[8], wb[9]};
        for (int i = 0; i < 12; ++i) { ca.s[i] = srcs[i]; ca.d[i] = dsts[i]; }
        cvt_all_kernel<<<dim3(12288), blk, 0, stream>>>(ca);
    }

    // ---- self-attention block ----
    // QKV fused: N=3072, chunks {Q,K,V}, rowmask on chunk 1 (K).
    gemm8ph_kernel<256><<<dim3(16, 12, 1), blk512, 0, stream>>>(
        abf, wb[0], sa_bq, sa_bk, sa_bv, sa_bv, sa_pad, 0x2u,
        Qb, Kb, Vb, Vb, D_MOD, nf, nff, nff, NTOK, 3072, D_MOD, 0, 1);
    vtrans_kernel<<<g_attn, blk, 0, stream>>>(Vb, Vt);
    flash_mfma_kernel<<<g_attn, blk, 0, stream>>>(Qb, Kb, Vt, Cb, nff, 1);
    // SA out-proj: split-K2 (z0 -> Yf +bias+resid, z1 -> Pq raw)
    gemm8ph_kernel<128><<<dim3(16, 8, 2), blk512, 0, stream>>>(
        Cb, wb[3], sa_bo, sa_bo, sa_bo, sa_bo, ni, 0u,
        nbf, nbf, nbf, nbf, D_MOD, x0, Yf, Pq, NTOK, D_MOD, D_MOD, 0, 2);
    layernorm_kernel<<<dim3(NTOK), blk, 0, stream>>>(Yf, Pq, ln1_g, ln1_b, X1f, abf);

    // ---- encoder-decoder attention block ----
    gemm8ph_kernel<128><<<dim3(16, 8, 1), blk512, 0, stream>>>(
        abf, wb[4], ea_bq, ea_bq, ea_bq, ea_bq, ni, 0u,
        Qb, Qb, Qb, Qb, D_MOD, nf, nff, nff, NTOK, D_MOD, D_MOD, 0, 1);
    gemm8ph_kernel<128><<<dim3(16, 16, 1), blk512, 0, stream>>>(
        ebf, wb[5], ea_bk, ea_bv, ea_bv, ea_bv, ea_pad, 0x1u,
        Kb, Vb, Vb, Vb, D_MOD, nf, nff, nff, NTOK, 2048, D_MOD, 0, 1);
    vtrans_kernel<<<g_attn, blk, 0, stream>>>(Vb, Vt);
    flash_mfma_kernel<<<g_attn, blk, 0, stream>>>(Qb, Kb, Vt, Cb, outa, 0);
    gemm8ph_kernel<128><<<dim3(16, 8, 2), blk512, 0, stream>>>(
        Cb, wb[7], ea_bo, ea_bo, ea_bo, ea_bo, ni, 0u,
        nbf, nbf, nbf, nbf, D_MOD, X1f, Yf, Pq, NTOK, D_MOD, D_MOD, 0, 2);
    layernorm_kernel<<<dim3(NTOK), blk, 0, stream>>>(Yf, Pq, ln2_g, ln2_b, X1f, ebf);

    // ---- FFN block ----
    gemm8ph_kernel<256><<<dim3(16, 16, 1), blk512, 0, stream>>>(
        ebf, wb[8], fc1_b, fc1_b + 1024, fc1_b + 2048, fc1_b + 3072, ni, 0u,
        Hbf, Hbf + 1024, Hbf + 2048, Hbf + 3072, FFN_D, nf, nff, nff,
        NTOK, FFN_D, D_MOD, 1, 1);
    gemm8ph_kernel<128><<<dim3(16, 8, 2), blk512, 0, stream>>>(
        Hbf, wb[9], fc2_b, fc2_b, fc2_b, fc2_b, ni, 0u,
        nbf, nbf, nbf, nbf, D_MOD, X1f, Yf, Pa, NTOK, D_MOD, FFN_D, 0, 2);
    layernorm_kernel<<<dim3(NTOK), blk, 0, stream>>>(Yf, Pa, ln3_g, ln3_b, outx, nbf);
}

// Round 8
// 619.161 us; speedup vs baseline: 2.8980x; 1.1040x over previous
//
#include <hip/hip_runtime.h>
#include <hip/hip_bf16.h>

// ---------------------------------------------------------------------------
// TransformerDecoderLayer on MI355X (gfx950). fp32 I/O, bf16 MFMA GEMMs with
// fp32 accumulation, MFMA flash attention, fp32 LayerNorm.
// Round 8: flash v3 — XCD-local grid (bh fast dim), swapped QK^T in-lane
// softmax (2 shfl instead of 32); GEMM BN=128 2-phase merge; vmcnt(4) fix.
// ---------------------------------------------------------------------------

typedef __attribute__((ext_vector_type(8))) short bf16x8;
typedef __attribute__((ext_vector_type(4))) float f32x4;
typedef __attribute__((ext_vector_type(8))) unsigned short us8;
typedef __attribute__((ext_vector_type(4))) unsigned short us4;

#define AS1 __attribute__((address_space(1)))
#define AS3 __attribute__((address_space(3)))

#define T_LEN 1024
#define S_LEN 1024
#define B_DIM 4
#define D_MOD 1024
#define H_NUM 16
#define FFN_D 4096
#define NTOK  4096

__device__ __forceinline__ float b2f(unsigned short u) {
    return __uint_as_float(((unsigned int)u) << 16);
}
__device__ __forceinline__ unsigned short f2b(float f) {
    unsigned int x = __float_as_uint(f);
    x += 0x7fffu + ((x >> 16) & 1u);   // RNE
    return (unsigned short)(x >> 16);
}

// ---------------------------------------------------------------------------
// Fused fp32 -> bf16 conversion of all 12 tensors in one launch.
// ---------------------------------------------------------------------------
struct CvtArgs {
    const float* s[12];
    unsigned short* d[12];
};

__global__ __launch_bounds__(256) void cvt_all_kernel(CvtArgs a)
{
    const int cnt[12] = {2048, 2048, 512, 512, 512, 512, 512, 512, 512, 512, 2048, 2048};
    int bid = blockIdx.x;
    int seg = 0;
    while (bid >= cnt[seg]) { bid -= cnt[seg]; ++seg; }
    const size_t off = (size_t)bid * 2048 + threadIdx.x * 8;
    const float* src = a.s[seg] + off;
    unsigned short* dst = a.d[seg] + off;
    const f32x4 v0 = *(const f32x4*)src;
    const f32x4 v1 = *(const f32x4*)(src + 4);
    us8 o;
#pragma unroll
    for (int j = 0; j < 4; ++j) { o[j] = f2b(v0[j]); o[4 + j] = f2b(v1[j]); }
    *(us8*)dst = o;
}

// ---------------------------------------------------------------------------
// gemm8ph: out[M,N] = A[M,K](bf16) @ W[N,K]^T(bf16), 256 x BN tile, BK=64,
// 8 waves (2M x 4N), 512 threads, double-buffered LDS, counted vmcnt,
// T2 swizzle, T5 setprio. BN=256: 4 phases/K-tile; BN=128: 2 merged phases.
// ---------------------------------------------------------------------------
template <int BN>
__global__ __launch_bounds__(512, 1) void gemm8ph_kernel(
    const unsigned short* __restrict__ A,
    const unsigned short* __restrict__ W,
    const float* __restrict__ b0, const float* __restrict__ b1,
    const float* __restrict__ b2, const float* __restrict__ b3,
    const int* __restrict__ rowmask, unsigned int maskbits,
    unsigned short* __restrict__ p0, unsigned short* __restrict__ p1,
    unsigned short* __restrict__ p2, unsigned short* __restrict__ p3,
    int ostride,
    const float* __restrict__ resid, float* __restrict__ outf,
    float* __restrict__ partf,
    int M, int N, int K, int relu, int ksplit)
{
    constexpr int NR  = BN / 64;          // B col-frags per wave (4 or 2)
    constexpr int BLH = (BN * 64) / 8192; // gload_lds per B half (2 or 1)
    constexpr int BBUF = BN * 128;        // bytes per B buffer

    __shared__ __align__(16) char ldsb[65536 + 2 * BBUF];

    const int tid  = threadIdx.x;
    const int lane = tid & 63;
    const int wid  = tid >> 6;
    const int wr   = wid >> 2;            // 0..1
    const int wc   = wid & 3;             // 0..3
    const int row0 = blockIdx.x * 256;
    const int col0 = blockIdx.y * BN;
    const int rsel = lane & 15;
    const int kg2  = (lane >> 4) * 16;    // k-group byte offset in 64B
    const int kz   = blockIdx.z;
    const int Keff = K / ksplit;
    const int koff = kz * Keff;
    const int NT   = Keff >> 6;

    f32x4 acc[8][NR];
#pragma unroll
    for (int m = 0; m < 8; ++m)
#pragma unroll
        for (int n = 0; n < NR; ++n)
            acc[m][n] = (f32x4){0.f, 0.f, 0.f, 0.f};

    auto stageA = [&](int buf, int half, int t) {
        const int k0 = koff + (t << 6);
#pragma unroll
        for (int i = 0; i < 2; ++i) {
            const unsigned int beta = (unsigned int)(half * 16384 + i * 8192 + tid * 16);
            const unsigned int lam  = beta ^ (((beta >> 7) & 7u) << 4);
            const char* src = (const char*)A +
                ((size_t)(row0 + (int)(lam >> 7)) * K + k0) * 2 + (lam & 127u);
            __builtin_amdgcn_global_load_lds((const AS1 void*)src,
                (AS3 void*)(ldsb + buf * 32768 + beta), 16, 0, 0);
        }
    };
    auto stageB = [&](int buf, int half, int t) {
        const int k0 = koff + (t << 6);
#pragma unroll
        for (int i = 0; i < BLH; ++i) {
            const unsigned int beta = (unsigned int)(half * (BN * 64) + i * 8192 + tid * 16);
            const unsigned int lam  = beta ^ (((beta >> 7) & 7u) << 4);
            const char* src = (const char*)W +
                ((size_t)(col0 + (int)(lam >> 7)) * K + k0) * 2 + (lam & 127u);
            __builtin_amdgcn_global_load_lds((const AS1 void*)src,
                (AS3 void*)(ldsb + 65536 + buf * BBUF + beta), 16, 0, 0);
        }
    };
    auto readA = [&](int buf, int m, int k) -> bf16x8 {
        const int r = wr * 128 + m * 16 + rsel;
        const unsigned int l  = (unsigned int)(r * 128 + k * 64 + kg2);
        const unsigned int ph = l ^ (((unsigned int)(r & 7)) << 4);
        return *(const bf16x8*)(ldsb + buf * 32768 + ph);
    };
    auto readB = [&](int buf, int n, int k) -> bf16x8 {
        const int r = wc * (BN / 4) + n * 16 + rsel;
        const unsigned int l  = (unsigned int)(r * 128 + k * 64 + kg2);
        const unsigned int ph = l ^ (((unsigned int)(r & 7)) << 4);
        return *(const bf16x8*)(ldsb + 65536 + buf * BBUF + ph);
    };

    // ---- prologue: tile0 (A+B), tile1 (A only) ----
    stageA(0, 0, 0); stageA(0, 1, 0); stageB(0, 0, 0); stageB(0, 1, 0);
    stageA(1, 0, 1); stageA(1, 1, 1);
    asm volatile("s_waitcnt vmcnt(4)" ::: "memory");   // A0,B0 landed; A1 in flight
    __builtin_amdgcn_s_barrier();

    if constexpr (NR == 2) {
        // ================= 2 merged phases per K-tile =================
        bf16x8 Af[8][2], Bf[2][2];
        for (int t = 0; t < NT; ++t) {
            const int cur = t & 1;
            // ---- phase 1: all A reads + B k0; stage B(t+1) ----
#pragma unroll
            for (int m = 0; m < 8; ++m) { Af[m][0] = readA(cur, m, 0); Af[m][1] = readA(cur, m, 1); }
#pragma unroll
            for (int n = 0; n < 2; ++n) Bf[n][0] = readB(cur, n, 0);
            if (t + 1 < NT) { stageB(cur ^ 1, 0, t + 1); stageB(cur ^ 1, 1, t + 1); }
            __builtin_amdgcn_s_barrier();
            asm volatile("s_waitcnt lgkmcnt(0)" ::: "memory");
            __builtin_amdgcn_sched_barrier(0);
            __builtin_amdgcn_s_setprio(1);
#pragma unroll
            for (int m = 0; m < 8; ++m)
#pragma unroll
                for (int n = 0; n < 2; ++n)
                    acc[m][n] = __builtin_amdgcn_mfma_f32_16x16x32_bf16(Af[m][0], Bf[n][0], acc[m][n], 0, 0, 0);
            __builtin_amdgcn_s_setprio(0);
            __builtin_amdgcn_s_barrier();
            // ---- phase 2: B k1 reads; stage A(t+2) ----
#pragma unroll
            for (int n = 0; n < 2; ++n) Bf[n][1] = readB(cur, n, 1);
            if (t + 2 < NT) { stageA(cur, 0, t + 2); stageA(cur, 1, t + 2); }
            __builtin_amdgcn_s_barrier();
            asm volatile("s_waitcnt lgkmcnt(0)" ::: "memory");
            __builtin_amdgcn_sched_barrier(0);
            __builtin_amdgcn_s_setprio(1);
#pragma unroll
            for (int m = 0; m < 8; ++m)
#pragma unroll
                for (int n = 0; n < 2; ++n)
                    acc[m][n] = __builtin_amdgcn_mfma_f32_16x16x32_bf16(Af[m][1], Bf[n][1], acc[m][n], 0, 0, 0);
            __builtin_amdgcn_s_setprio(0);
            if (t + 2 < NT) { asm volatile("s_waitcnt vmcnt(4)" ::: "memory"); }
            else            { asm volatile("s_waitcnt vmcnt(0)" ::: "memory"); }
            __builtin_amdgcn_s_barrier();
        }
    } else {
        // ================= 4 phases per K-tile (BN=256) =================
        bf16x8 Afr[8][2], Bfr[NR][2];
        for (int t = 0; t < NT; ++t) {
            const int cur = t & 1;
            // ---------------- phase 1 ----------------
#pragma unroll
            for (int m = 0; m < 4; ++m) { Afr[m][0] = readA(cur, m, 0); Afr[m][1] = readA(cur, m, 1); }
#pragma unroll
            for (int n = 0; n < NR; ++n) Bfr[n][0] = readB(cur, n, 0);
            if (t + 1 < NT) stageB(cur ^ 1, 0, t + 1);
            __builtin_amdgcn_s_barrier();
            asm volatile("s_waitcnt lgkmcnt(0)" ::: "memory");
            __builtin_amdgcn_sched_barrier(0);
            __builtin_amdgcn_s_setprio(1);
#pragma unroll
            for (int m = 0; m < 4; ++m)
#pragma unroll
                for (int n = 0; n < NR; ++n)
                    acc[m][n] = __builtin_amdgcn_mfma_f32_16x16x32_bf16(Afr[m][0], Bfr[n][0], acc[m][n], 0, 0, 0);
            __builtin_amdgcn_s_setprio(0);
            __builtin_amdgcn_s_barrier();
            // ---------------- phase 2 ----------------
#pragma unroll
            for (int m = 4; m < 8; ++m) { Afr[m][0] = readA(cur, m, 0); Afr[m][1] = readA(cur, m, 1); }
#pragma unroll
            for (int n = 0; n < NR; ++n) Bfr[n][1] = readB(cur, n, 1);
            if (t + 1 < NT) stageB(cur ^ 1, 1, t + 1);
            __builtin_amdgcn_s_barrier();
            asm volatile("s_waitcnt lgkmcnt(0)" ::: "memory");
            __builtin_amdgcn_sched_barrier(0);
            __builtin_amdgcn_s_setprio(1);
#pragma unroll
            for (int m = 4; m < 8; ++m)
#pragma unroll
                for (int n = 0; n < NR; ++n)
                    acc[m][n] = __builtin_amdgcn_mfma_f32_16x16x32_bf16(Afr[m][0], Bfr[n][0], acc[m][n], 0, 0, 0);
            __builtin_amdgcn_s_setprio(0);
            __builtin_amdgcn_s_barrier();
            // ---------------- phase 3 ----------------
            if (t + 2 < NT) stageA(cur, 0, t + 2);
            __builtin_amdgcn_s_barrier();
            __builtin_amdgcn_s_setprio(1);
#pragma unroll
            for (int m = 0; m < 4; ++m)
#pragma unroll
                for (int n = 0; n < NR; ++n)
                    acc[m][n] = __builtin_amdgcn_mfma_f32_16x16x32_bf16(Afr[m][1], Bfr[n][1], acc[m][n], 0, 0, 0);
            __builtin_amdgcn_s_setprio(0);
            __builtin_amdgcn_s_barrier();
            // ---------------- phase 4 ----------------
            if (t + 2 < NT) stageA(cur, 1, t + 2);
            __builtin_amdgcn_s_barrier();
            __builtin_amdgcn_s_setprio(1);
#pragma unroll
            for (int m = 4; m < 8; ++m)
#pragma unroll
                for (int n = 0; n < NR; ++n)
                    acc[m][n] = __builtin_amdgcn_mfma_f32_16x16x32_bf16(Afr[m][1], Bfr[n][1], acc[m][n], 0, 0, 0);
            __builtin_amdgcn_s_setprio(0);
            if (t + 2 < NT) { asm volatile("s_waitcnt vmcnt(4)" ::: "memory"); }
            else            { asm volatile("s_waitcnt vmcnt(0)" ::: "memory"); }
            __builtin_amdgcn_s_barrier();
        }
    }

    // ---- epilogue ----
    const int seq  = M >> 2;
    const int c    = col0 >> 10;
    unsigned short* op = c == 0 ? p0 : c == 1 ? p1 : c == 2 ? p2 : p3;
    const float*    bp = c == 0 ? b0 : c == 1 ? b1 : c == 2 ? b2 : b3;
    const bool um = rowmask && ((maskbits >> c) & 1u);
    const int rbas = (lane >> 4) * 4;
    if (partf && kz > 0) {
#pragma unroll
        for (int m = 0; m < 8; ++m)
#pragma unroll
            for (int n = 0; n < NR; ++n)
#pragma unroll
                for (int j = 0; j < 4; ++j) {
                    const int gr = row0 + wr * 128 + m * 16 + rbas + j;
                    const int gc = col0 + wc * (BN / 4) + n * 16 + rsel;
                    partf[(size_t)gr * N + gc] = acc[m][n][j];
                }
    } else {
#pragma unroll
        for (int m = 0; m < 8; ++m)
#pragma unroll
            for (int n = 0; n < NR; ++n)
#pragma unroll
                for (int j = 0; j < 4; ++j) {
                    const int gr = row0 + wr * 128 + m * 16 + rbas + j;
                    const int gc = col0 + wc * (BN / 4) + n * 16 + rsel;
                    float v = acc[m][n][j];
                    if (um && rowmask[(gr & 3) * seq + (gr >> 2)] != 0) v = 0.f;
                    v += bp[gc & 1023];
                    if (relu) v = fmaxf(v, 0.f);
                    if (resid) v += resid[(size_t)gr * N + gc];
                    if (outf) outf[(size_t)gr * N + gc] = v;
                    else      op[(size_t)gr * ostride + (gc & 1023)] = f2b(v);
                }
    }
}

// ---------------------------------------------------------------------------
// V transpose: Vb[tok][D] (bf16) -> Vt[(b*H+h)*64+d][T] (bf16).
// Grid: (bh, t-tile) so same-bh WGs colocate per XCD.
// ---------------------------------------------------------------------------
__global__ __launch_bounds__(256) void vtrans_kernel(
    const unsigned short* __restrict__ Vb, unsigned short* __restrict__ Vt)
{
    __shared__ unsigned short tile[64 * 72];
    const int tid = threadIdx.x;
    const int bh  = blockIdx.x;          // b*H + h
    const int t0  = blockIdx.y * 64;
    const int h   = bh & (H_NUM - 1);
    const int b   = bh >> 4;

    const int r   = tid >> 2;            // 0..63 (t-local)
    const int c16 = (tid & 3) * 16;      // d-chunk
    const unsigned short* src = Vb + ((size_t)(t0 + r) * B_DIM + b) * D_MOD + h * 64 + c16;
    *(us8*)&tile[r * 72 + c16]     = *(const us8*)src;
    *(us8*)&tile[r * 72 + c16 + 8] = *(const us8*)(src + 8);
    __syncthreads();

    const int dr  = tid >> 2;            // 0..63 (d-local)
    const int tch = (tid & 3) * 16;      // t-chunk
    us8 o0, o1;
#pragma unroll
    for (int j = 0; j < 8; ++j) {
        o0[j] = tile[(tch + j) * 72 + dr];
        o1[j] = tile[(tch + 8 + j) * 72 + dr];
    }
    unsigned short* dst = Vt + (size_t)(bh * 64 + dr) * S_LEN + t0 + tch;
    *(us8*)dst       = o0;
    *(us8*)(dst + 8) = o1;
}

// ---------------------------------------------------------------------------
// MFMA flash attention v3. WG = 4 waves x 16 q-rows (QBLK=64) for one (b,h).
// Grid: (bh, t-tile) -> xcd = bh%8, K/V L2-local per XCD.
// Swapped QK^T: sacc = mfma(K, Q) puts P in-lane per q-row (q = lane&15,
// s = u*16 + g*4 + j) -> softmax = 16 in-lane ops + 2 shfl_xor; m/l scalars.
// PV unchanged (P via per-wave LDS, packed b32 writes).
// ---------------------------------------------------------------------------
__global__ __launch_bounds__(256, 3) void flash_mfma_kernel(
    const unsigned short* __restrict__ Qb,
    const unsigned short* __restrict__ Kb,
    const unsigned short* __restrict__ Vt,
    unsigned short* __restrict__ outc,
    float* __restrict__ outp,
    int causal)
{
    __shared__ __align__(16) unsigned short Ks[2][64 * 64];   // swizzled
    __shared__ __align__(16) unsigned short Vts[2][64 * 64];  // swizzled
    __shared__ __align__(16) unsigned short Ps[4][16 * 72];   // per-wave P

    const int tid  = threadIdx.x;
    const int lane = tid & 63;
    const int wv   = tid >> 6;
    const int g    = lane >> 4;          // 0..3
    const int n    = lane & 15;          // 0..15
    const int g4   = g * 4;
    const int bh   = blockIdx.x;
    const int t0   = blockIdx.y * 64;
    const int h    = bh & (H_NUM - 1);
    const int b    = bh >> 4;
    const int woff = wv * 16;

    // Q fragment (row = lane&15 = q-local, k = g*8), used as B operand
    bf16x8 qa[2];
    {
        const unsigned short* qptr =
            Qb + ((size_t)(t0 + woff + n) * B_DIM + b) * D_MOD + h * 64 + g * 8;
        qa[0] = *(const bf16x8*)qptr;
        qa[1] = *(const bf16x8*)(qptr + 32);
    }

    f32x4 ctx[4];
#pragma unroll
    for (int nt = 0; nt < 4; ++nt) ctx[nt] = (f32x4){0.f, 0.f, 0.f, 0.f};
    float m_run = -INFINITY, l_run = 0.f;   // for q = t0+woff+n (this lane)

    unsigned short* pw = &Ps[wv][0];
    const int smax = causal ? (t0 + 64) : S_LEN;
    const int NTt  = smax >> 6;
    const int tq   = t0 + woff + n;

    auto stage = [&](int buf, int s0) {
#pragma unroll
        for (int i = 0; i < 2; ++i) {
            const unsigned int beta = (unsigned int)(i * 4096 + tid * 16);
            const unsigned int lam  = beta ^ (((beta >> 7) & 7u) << 4);
            const int row = (int)(lam >> 7);           // 0..63
            const unsigned int colb = lam & 127u;
            const char* srcK = (const char*)Kb +
                ((size_t)((s0 + row) * B_DIM + b) * D_MOD + h * 64) * 2 + colb;
            __builtin_amdgcn_global_load_lds((const AS1 void*)srcK,
                (AS3 void*)((char*)&Ks[buf][0] + beta), 16, 0, 0);
            const char* srcV = (const char*)Vt +
                ((size_t)(bh * 64 + row) * S_LEN + s0) * 2 + colb;
            __builtin_amdgcn_global_load_lds((const AS1 void*)srcV,
                (AS3 void*)((char*)&Vts[buf][0] + beta), 16, 0, 0);
        }
    };

    stage(0, 0);
    for (int t = 0; t < NTt; ++t) {
        const int s0  = t << 6;
        const int cur = t & 1;
        asm volatile("s_waitcnt vmcnt(0)" ::: "memory");
        __builtin_amdgcn_s_barrier();
        if (t + 1 < NTt) stage(cur ^ 1, s0 + 64);

        // ---- S^T = K Q^T : 4 s-subtiles x 2 k-chunks ----
        f32x4 sacc[4];
#pragma unroll
        for (int u = 0; u < 4; ++u) sacc[u] = (f32x4){0.f, 0.f, 0.f, 0.f};
#pragma unroll
        for (int u = 0; u < 4; ++u) {
#pragma unroll
            for (int kc = 0; kc < 2; ++kc) {
                const int r = u * 16 + n;
                const unsigned int l  = (unsigned int)(r * 128 + kc * 64 + g * 16);
                const unsigned int ph = l ^ (((unsigned int)(r & 7)) << 4);
                const bf16x8 kb = *(const bf16x8*)((const char*)&Ks[cur][0] + ph);
                sacc[u] = __builtin_amdgcn_mfma_f32_16x16x32_bf16(kb, qa[kc], sacc[u], 0, 0, 0);
            }
        }

        // ---- in-lane online softmax: P[s = s0+u*16+g4+j][q = tq] ----
        const bool diag = causal && (s0 + 64 > t0);
        float pv[4][4];
        float pm = -INFINITY;
#pragma unroll
        for (int u = 0; u < 4; ++u)
#pragma unroll
            for (int j = 0; j < 4; ++j) {
                float p = sacc[u][j] * 0.125f;
                if (diag && (s0 + u * 16 + g4 + j > tq)) p += -1e9f;
                pv[u][j] = p;
                pm = fmaxf(pm, p);
            }
        pm = fmaxf(pm, __shfl_xor(pm, 16));
        pm = fmaxf(pm, __shfl_xor(pm, 32));
        const float m_new = fmaxf(m_run, pm);
        const float sc = __expf(m_run - m_new);
        m_run = m_new;
        float ls = 0.f;
#pragma unroll
        for (int u = 0; u < 4; ++u) {
            const float e0 = __expf(pv[u][0] - m_new);
            const float e1 = __expf(pv[u][1] - m_new);
            const float e2 = __expf(pv[u][2] - m_new);
            const float e3 = __expf(pv[u][3] - m_new);
            ls += (e0 + e1) + (e2 + e3);
            const unsigned int w0 = (unsigned int)f2b(e0) | ((unsigned int)f2b(e1) << 16);
            const unsigned int w1 = (unsigned int)f2b(e2) | ((unsigned int)f2b(e3) << 16);
            *(unsigned int*)&pw[n * 72 + u * 16 + g4]     = w0;
            *(unsigned int*)&pw[n * 72 + u * 16 + g4 + 2] = w1;
        }
        ls += __shfl_xor(ls, 16);
        ls += __shfl_xor(ls, 32);
        l_run = l_run * sc + ls;

        // broadcast rescale to ctx rows (q = g4+j lives at lane g4+j)
        float scq[4];
#pragma unroll
        for (int j = 0; j < 4; ++j) scq[j] = __shfl(sc, g4 + j);
#pragma unroll
        for (int nt = 0; nt < 4; ++nt)
#pragma unroll
            for (int j = 0; j < 4; ++j) ctx[nt][j] *= scq[j];

        // ---- ctx += P V : A-frag from P LDS, B-frag from V^T ----
        bf16x8 pa[2];
#pragma unroll
        for (int ks = 0; ks < 2; ++ks)
            pa[ks] = *(const bf16x8*)&pw[n * 72 + ks * 32 + g * 8];
#pragma unroll
        for (int nt = 0; nt < 4; ++nt) {
#pragma unroll
            for (int ks = 0; ks < 2; ++ks) {
                const int r = nt * 16 + n;
                const unsigned int l  = (unsigned int)(r * 128 + ks * 64 + g * 16);
                const unsigned int ph = l ^ (((unsigned int)(r & 7)) << 4);
                const bf16x8 vb = *(const bf16x8*)((const char*)&Vts[cur][0] + ph);
                ctx[nt] = __builtin_amdgcn_mfma_f32_16x16x32_bf16(pa[ks], vb, ctx[nt], 0, 0, 0);
            }
        }
    }

    // ---- epilogue (ctx: q = t0+woff+g4+j, d = nt*16+n) ----
    float invq[4];
#pragma unroll
    for (int j = 0; j < 4; ++j) invq[j] = 1.f / __shfl(l_run, g4 + j);
#pragma unroll
    for (int nt = 0; nt < 4; ++nt) {
#pragma unroll
        for (int j = 0; j < 4; ++j) {
            const int t = t0 + woff + g4 + j;
            const int d = nt * 16 + n;
            const float v = ctx[nt][j] * invq[j];
            outc[((size_t)t * B_DIM + b) * D_MOD + h * 64 + d] = f2b(v);
            if (outp)
                outp[((size_t)(h * B_DIM + b) * T_LEN + t) * 64 + d] = v;
        }
    }
}

// ---------------------------------------------------------------------------
// LayerNorm over D=1024 (fp32 in + optional f32 partial, f32/bf16 out).
// ---------------------------------------------------------------------------
__global__ __launch_bounds__(256) void layernorm_kernel(
    const float* __restrict__ y,
    const float* __restrict__ part,
    const float* __restrict__ g,
    const float* __restrict__ be,
    float* __restrict__ out_f,
    unsigned short* __restrict__ out_bf)
{
    __shared__ float red[8];
    const int row = blockIdx.x;
    const int tid = threadIdx.x;
    f32x4 v = *(const f32x4*)&y[(size_t)row * D_MOD + tid * 4];
    if (part) {
        const f32x4 pv = *(const f32x4*)&part[(size_t)row * D_MOD + tid * 4];
#pragma unroll
        for (int j = 0; j < 4; ++j) v[j] += pv[j];
    }
    float s = v[0] + v[1] + v[2] + v[3];
#pragma unroll
    for (int o = 32; o > 0; o >>= 1) s += __shfl_xor(s, o);
    if ((tid & 63) == 0) red[tid >> 6] = s;
    __syncthreads();
    const float mu = (red[0] + red[1] + red[2] + red[3]) * (1.f / D_MOD);
    const float d0 = v[0] - mu, d1 = v[1] - mu, d2 = v[2] - mu, d3 = v[3] - mu;
    float s2 = d0 * d0 + d1 * d1 + d2 * d2 + d3 * d3;
#pragma unroll
    for (int o = 32; o > 0; o >>= 1) s2 += __shfl_xor(s2, o);
    if ((tid & 63) == 0) red[4 + (tid >> 6)] = s2;
    __syncthreads();
    const float var  = (red[4] + red[5] + red[6] + red[7]) * (1.f / D_MOD);
    const float rstd = rsqrtf(var + 1e-5f);
    const float dd[4] = {d0, d1, d2, d3};
    f32x4 of;
    us4 ob;
#pragma unroll
    for (int j = 0; j < 4; ++j) {
        const int col = tid * 4 + j;
        const float r = dd[j] * rstd * g[col] + be[col];
        of[j] = r;
        ob[j] = f2b(r);
    }
    const size_t oi = (size_t)row * D_MOD + tid * 4;
    if (out_f)  *(f32x4*)&out_f[oi] = of;
    if (out_bf) *(us4*)&out_bf[oi]  = ob;
}

// ---------------------------------------------------------------------------
extern "C" void kernel_launch(void* const* d_in, const int* in_sizes, int n_in,
                              void* d_out, int out_size, void* d_ws, size_t ws_size,
                              hipStream_t stream) {
    (void)in_sizes; (void)n_in; (void)out_size; (void)ws_size;

    const float* x0    = (const float*)d_in[0];
    const float* enc   = (const float*)d_in[1];
    const int* sa_pad  = (const int*)d_in[3];
    const int* ea_pad  = (const int*)d_in[4];
    const float* sa_Wq = (const float*)d_in[5];
    const float* sa_bq = (const float*)d_in[6];
    const float* sa_Wk = (const float*)d_in[7];
    const float* sa_bk = (const float*)d_in[8];
    const float* sa_Wv = (const float*)d_in[9];
    const float* sa_bv = (const float*)d_in[10];
    const float* sa_Wo = (const float*)d_in[11];
    const float* sa_bo = (const float*)d_in[12];
    const float* ea_Wq = (const float*)d_in[13];
    const float* ea_bq = (const float*)d_in[14];
    const float* ea_Wk = (const float*)d_in[15];
    const float* ea_bk = (const float*)d_in[16];
    const float* ea_Wv = (const float*)d_in[17];
    const float* ea_bv = (const float*)d_in[18];
    const float* ea_Wo = (const float*)d_in[19];
    const float* ea_bo = (const float*)d_in[20];
    const float* ln1_g = (const float*)d_in[21];
    const float* ln1_b = (const float*)d_in[22];
    const float* ln2_g = (const float*)d_in[23];
    const float* ln2_b = (const float*)d_in[24];
    const float* ln3_g = (const float*)d_in[25];
    const float* ln3_b = (const float*)d_in[26];
    const float* fc1_W = (const float*)d_in[27];
    const float* fc1_b = (const float*)d_in[28];
    const float* fc2_W = (const float*)d_in[29];
    const float* fc2_b = (const float*)d_in[30];

    // ---- workspace layout (elements) ----
    const size_t DD = (size_t)D_MOD * D_MOD;    // 1,048,576
    const size_t FD = (size_t)FFN_D * D_MOD;    // 4,194,304
    const size_t SL = (size_t)NTOK * D_MOD;     // 4,194,304

    unsigned short* ws_us = (unsigned short*)d_ws;
    unsigned short* wb[10];
    for (int i = 0; i < 8; ++i) wb[i] = ws_us + i * DD;
    wb[8] = ws_us + 8 * DD;           // fc1_W bf16 (FD)
    wb[9] = ws_us + 8 * DD + FD;      // fc2_W bf16 (FD)
    unsigned short* abf = ws_us + 8 * DD + 2 * FD;   // x0 bf16, later X1 bf16
    unsigned short* ebf = abf + SL;   // enc bf16, later X2 bf16
    unsigned short* Cb  = ebf + SL;   // attn ctx bf16
    unsigned short* Qb  = Cb + SL;    // Q bf16          (Hbf overlays Qb..Vt)
    unsigned short* Kb  = Qb + SL;    // K bf16
    unsigned short* Vb  = Kb + SL;    // V bf16
    unsigned short* Vt  = Vb + SL;    // V^T bf16 [(b*H+h)*64+d][S]
    unsigned short* Hbf = Qb;         // [NTOK, FFN] bf16 = 4*SL elements
    float* fbase = (float*)(Vt + SL);
    float* Yf  = fbase;               // pre-LN accumulator (f32)
    float* X1f = fbase + SL;          // LN1/LN2 out (f32)
    float* Pq  = (float*)Qb;          // split-K partial (over Qb..Kb, dead then)
    float* Pa  = (float*)abf;         // split-K partial for fc2 (abf+ebf dead then)

    float* outx = (float*)d_out;      // x [T,B,D]
    float* outa = outx + SL;          // attn [H,B,T,HD]

    const dim3 blk(256);
    const dim3 blk512(512);
    const dim3 g_attn(B_DIM * H_NUM, T_LEN / 64); // (64 bh, 16 t) -> xcd=bh%8
    unsigned short* nbf = nullptr;
    float* nff = nullptr;
    const float* nf = nullptr;
    const int* ni = nullptr;

    // ---- fused fp32 -> bf16 conversion (1 launch, 12 segments) ----
    {
        CvtArgs ca;
        const float* srcs[12]  = {x0, enc, sa_Wq, sa_Wk, sa_Wv, sa_Wo,
                                  ea_Wq, ea_Wk, ea_Wv, ea_Wo, fc1_W, fc2_W};
        unsigned short* dsts[12] = {abf, ebf, wb[0], wb[1], wb[2], wb[3],
                                    wb[4], wb[5], wb[6], wb[7], wb[8], wb[9]};
        for (int i = 0; i < 12; ++i) { ca.s[i] = srcs[i]; ca.d[i] = dsts[i]; }
        cvt_all_kernel<<<dim3(12288), blk, 0, stream>>>(ca);
    }

    // ---- self-attention block ----
    gemm8ph_kernel<256><<<dim3(16, 12, 1), blk512, 0, stream>>>(
        abf, wb[0], sa_bq, sa_bk, sa_bv, sa_bv, sa_pad, 0x2u,
        Qb, Kb, Vb, Vb, D_MOD, nf, nff, nff, NTOK, 3072, D_MOD, 0, 1);
    vtrans_kernel<<<g_attn, blk, 0, stream>>>(Vb, Vt);
    flash_mfma_kernel<<<g_attn, blk, 0, stream>>>(Qb, Kb, Vt, Cb, nff, 1);
    gemm8ph_kernel<128><<<dim3(16, 8, 2), blk512, 0, stream>>>(
        Cb, wb[3], sa_bo, sa_bo, sa_bo, sa_bo, ni, 0u,
        nbf, nbf, nbf, nbf, D_MOD, x0, Yf, Pq, NTOK, D_MOD, D_MOD, 0, 2);
    layernorm_kernel<<<dim3(NTOK), blk, 0, stream>>>(Yf, Pq, ln1_g, ln1_b, X1f, abf);

    // ---- encoder-decoder attention block ----
    gemm8ph_kernel<128><<<dim3(16, 8, 1), blk512, 0, stream>>>(
        abf, wb[4], ea_bq, ea_bq, ea_bq, ea_bq, ni, 0u,
        Qb, Qb, Qb, Qb, D_MOD, nf, nff, nff, NTOK, D_MOD, D_MOD, 0, 1);
    gemm8ph_kernel<128><<<dim3(16, 16, 1), blk512, 0, stream>>>(
        ebf, wb[5], ea_bk, ea_bv, ea_bv, ea_bv, ea_pad, 0x1u,
        Kb, Vb, Vb, Vb, D_MOD, nf, nff, nff, NTOK, 2048, D_MOD, 0, 1);
    vtrans_kernel<<<g_attn, blk, 0, stream>>>(Vb, Vt);
    flash_mfma_kernel<<<g_attn, blk, 0, stream>>>(Qb, Kb, Vt, Cb, outa, 0);
    gemm8ph_kernel<128><<<dim3(16, 8, 2), blk512, 0, stream>>>(
        Cb, wb[7], ea_bo, ea_bo, ea_bo, ea_bo, ni, 0u,
        nbf, nbf, nbf, nbf, D_MOD, X1f, Yf, Pq, NTOK, D_MOD, D_MOD, 0, 2);
    layernorm_kernel<<<dim3(NTOK), blk, 0, stream>>>(Yf, Pq, ln2_g, ln2_b, X1f, ebf);

    // ---- FFN block ----
    gemm8ph_kernel<256><<<dim3(16, 16, 1), blk512, 0, stream>>>(
        ebf, wb[8], fc1_b, fc1_b + 1024, fc1_b + 2048, fc1_b + 3072, ni, 0u,
        Hbf, Hbf + 1024, Hbf + 2048, Hbf + 3072, FFN_D, nf, nff, nff,
        NTOK, FFN_D, D_MOD, 1, 1);
    gemm8ph_kernel<128><<<dim3(16, 8, 2), blk512, 0, stream>>>(
        Hbf, wb[9], fc2_b, fc2_b, fc2_b, fc2_b, ni, 0u,
        nbf, nbf, nbf, nbf, D_MOD, X1f, Yf, Pa, NTOK, D_MOD, FFN_D, 0, 2);
    layernorm_kernel<<<dim3(NTOK), blk, 0, stream>>>(Yf, Pa, ln3_g, ln3_b, outx, nbf);
}